// Round 11
// baseline (494.265 us; speedup 1.0000x reference)
//
#include <hip/hip_runtime.h>
#include <math.h>

// Problem constants
#define NN 100000
#define EE 1600000
#define FIN 128
#define HCH 128     // H*C for gat1
#define CCH 32      // C
#define NCLONE 19
#define NTYPE 29
#define ETOT (EE + NN)
#define SCAN_B 49   // ceil(NN / 2048)
#define NBIN 128
#define LOG2E 1.4426950408889634f
#define QBIAS 5.0f

typedef __bf16 bf16_t;
typedef bf16_t bf16x8 __attribute__((ext_vector_type(8)));
typedef _Float16 fp16_t;
typedef fp16_t fp16x2 __attribute__((ext_vector_type(2)));
typedef fp16_t fp16x4 __attribute__((ext_vector_type(4)));
typedef fp16_t fp16x8 __attribute__((ext_vector_type(8)));
typedef float f32x4 __attribute__((ext_vector_type(4)));

static __device__ __forceinline__ fp16x2 shfl_p2(fp16x2 v, int mask) {
    float f = __shfl_xor(__builtin_bit_cast(float, v), mask, 64);
    return __builtin_bit_cast(fp16x2, f);
}
static __device__ __forceinline__ fp16x2 bc2(float f) {
    fp16_t h = (fp16_t)f;
    fp16x2 r = {h, h};
    return r;
}
// leaky_relu(w, 0.2) == 0.6*w + 0.4*|w|   (exact for both signs)
static __device__ __forceinline__ fp16x2 leaky2(fp16x2 w) {
    unsigned u = __builtin_bit_cast(unsigned, w) & 0x7FFF7FFFu;
    fp16x2 aw = __builtin_bit_cast(fp16x2, u);
    const fp16x2 c06 = {(fp16_t)0.6f, (fp16_t)0.6f};
    const fp16x2 c04 = {(fp16_t)0.4f, (fp16_t)0.4f};
    return c06 * w + c04 * aw;
}

// ---------------------------------------------------------------- weight conversion
__global__ __launch_bounds__(256) void k_wcvt(const float* __restrict__ Wl1,
                                              const float* __restrict__ Wr1,
                                              const float* __restrict__ Ws,
                                              const float* __restrict__ Wl2,
                                              const float* __restrict__ Wr2,
                                              bf16_t* __restrict__ WbT,
                                              bf16_t* __restrict__ Wb2T) {
    int t = blockIdx.x * 256 + threadIdx.x;
    if (t < 384 * 128) {
        int n = t >> 7, k = t & 127;
        const float* W = (n < 128) ? Wl1 : ((n < 256) ? Wr1 : Ws);
        WbT[t] = (bf16_t)W[k * 128 + (n & 127)];
    } else if (t < 384 * 128 + 64 * 128) {
        int u = t - 384 * 128;
        int n = u >> 7, k = u & 127;
        const float* W = (n < 32) ? Wl2 : Wr2;
        Wb2T[u] = (bf16_t)W[k * 32 + (n & 31)];
    }
}

// ---------------------------------------------------------------- degree + slot
__global__ __launch_bounds__(256) void k_deg(const int* __restrict__ ei,
                                             int* __restrict__ deg,
                                             int* __restrict__ slot) {
    int e = blockIdx.x * 256 + threadIdx.x;
    if (e < EE) {
        int d = ei[EE + e];
        slot[e] = atomicAdd(&deg[d], 1);
    }
}

// ---------------------------------------------------------------- degree histogram / scan / scatter (descending-degree perm)
__global__ __launch_bounds__(256) void k_hist(const int* __restrict__ deg,
                                              int* __restrict__ hist) {
    __shared__ int lh[NBIN];
    int tid = threadIdx.x;
    if (tid < NBIN) lh[tid] = 0;
    __syncthreads();
    int v = blockIdx.x * 256 + tid;
    if (v < NN) atomicAdd(&lh[min(deg[v], NBIN - 1)], 1);
    __syncthreads();
    if (tid < NBIN && lh[tid]) atomicAdd(&hist[tid], lh[tid]);
}

__global__ void k_bscan(const int* __restrict__ hist, int* __restrict__ binpos) {
    if (threadIdx.x == 0) {
        int run = 0;
        for (int b = NBIN - 1; b >= 0; --b) { binpos[b] = run; run += hist[b]; }
    }
}

__global__ __launch_bounds__(256) void k_scat(const int* __restrict__ deg,
                                              int* __restrict__ binpos,
                                              int* __restrict__ perm) {
    __shared__ int lcnt[NBIN];
    __shared__ int lbase[NBIN];
    int tid = threadIdx.x;
    if (tid < NBIN) lcnt[tid] = 0;
    __syncthreads();
    int v = blockIdx.x * 256 + tid;
    int b = 0, r = 0;
    bool ok = (v < NN);
    if (ok) {
        b = min(deg[v], NBIN - 1);
        r = atomicAdd(&lcnt[b], 1);
    }
    __syncthreads();
    if (tid < NBIN && lcnt[tid]) lbase[tid] = atomicAdd(&binpos[tid], lcnt[tid]);
    __syncthreads();
    if (ok) perm[lbase[b] + r] = v;
}

// ---------------------------------------------------------------- exclusive scan of deg
__global__ __launch_bounds__(256) void k_scan1(const int* __restrict__ deg,
                                               int* __restrict__ offs,
                                               int* __restrict__ bsum) {
    __shared__ int tsum[256];
    int b = blockIdx.x, tid = threadIdx.x;
    int base = b * 2048;
    int loc[8];
    int s = 0;
    #pragma unroll
    for (int i = 0; i < 8; ++i) {
        int idx = base + tid * 8 + i;
        int d = (idx < NN) ? deg[idx] : 0;
        loc[i] = s; s += d;
    }
    tsum[tid] = s;
    __syncthreads();
    for (int off = 1; off < 256; off <<= 1) {
        int v = (tid >= off) ? tsum[tid - off] : 0;
        __syncthreads();
        tsum[tid] += v;
        __syncthreads();
    }
    int texcl = tsum[tid] - s;
    #pragma unroll
    for (int i = 0; i < 8; ++i) {
        int idx = base + tid * 8 + i;
        if (idx < NN) offs[idx] = texcl + loc[i];
    }
    if (tid == 255) bsum[b] = tsum[255];
}

__global__ void k_scan2(int* __restrict__ bsum) {
    if (threadIdx.x == 0) {
        int run = 0;
        for (int i = 0; i < SCAN_B; ++i) { int t = bsum[i]; bsum[i] = run; run += t; }
    }
}

__global__ __launch_bounds__(256) void k_scan3(int* __restrict__ offs,
                                               const int* __restrict__ bsum) {
    int i = blockIdx.x * 256 + threadIdx.x;
    if (i < NN) offs[i] += bsum[i >> 11];
}

// ---------------------------------------------------------------- CSR fill (atomic-free)
__global__ __launch_bounds__(256) void k_fill(const int* __restrict__ ei,
                                              const float* __restrict__ ea,
                                              const int* __restrict__ offs,
                                              const int* __restrict__ slot,
                                              int2* __restrict__ ep8) {
    int e = blockIdx.x * 256 + threadIdx.x;
    if (e < EE) {
        int d = ei[EE + e];
        int pos = offs[d] + slot[e];
        ep8[pos] = make_int2(ei[e], __float_as_int(ea[e]));
    }
}

// ---------------------------------------------------------------- GEMM1 (MFMA): x(f32) @ WbT^T -> [xl1|xr1|skb] (fp16)
__global__ __launch_bounds__(256) void k_gemm1(const float* __restrict__ x,
                                               const bf16_t* __restrict__ WbT,
                                               fp16_t* __restrict__ xl,
                                               fp16_t* __restrict__ xr,
                                               fp16_t* __restrict__ sk) {
    __shared__ bf16_t As[128 * 128];
    __shared__ bf16_t Bs[128 * 128];
    const int tid = threadIdx.x;
    const int row0 = blockIdx.x * 128;
    #pragma unroll
    for (int i = 0; i < 8; ++i) {
        int c = i * 256 + tid;
        int r = c >> 4, g = c & 15;
        int gr = row0 + r;
        bf16x8 v = {};
        if (gr < NN) {
            float4 f0 = *(const float4*)(x + (size_t)gr * 128 + g * 8);
            float4 f1 = *(const float4*)(x + (size_t)gr * 128 + g * 8 + 4);
            v[0] = (bf16_t)f0.x; v[1] = (bf16_t)f0.y; v[2] = (bf16_t)f0.z; v[3] = (bf16_t)f0.w;
            v[4] = (bf16_t)f1.x; v[5] = (bf16_t)f1.y; v[6] = (bf16_t)f1.z; v[7] = (bf16_t)f1.w;
        }
        *(bf16x8*)&As[r * 128 + ((g ^ (r & 7)) * 8)] = v;
    }

    const int wid = tid >> 6, lane = tid & 63;
    const int wm = wid >> 1, wn = wid & 1;
    const int lr = lane & 15, lg = lane >> 4;

    for (int chunk = 0; chunk < 3; ++chunk) {
        const int col0 = chunk * 128;
        fp16_t* __restrict__ out = (chunk == 0) ? xl : ((chunk == 1) ? xr : sk);
        __syncthreads();
        #pragma unroll
        for (int i = 0; i < 8; ++i) {
            int c = i * 256 + tid;
            int n = c >> 4, g = c & 15;
            bf16x8 v = *(const bf16x8*)(WbT + (size_t)(col0 + n) * 128 + g * 8);
            *(bf16x8*)&Bs[n * 128 + ((g ^ (n & 7)) * 8)] = v;
        }
        __syncthreads();

        f32x4 acc[4][4] = {};
        #pragma unroll
        for (int ks = 0; ks < 4; ++ks) {
            int g = ks * 4 + lg;
            bf16x8 b[4];
            #pragma unroll
            for (int ni = 0; ni < 4; ++ni) {
                int n = wn * 64 + ni * 16 + lr;
                b[ni] = *(const bf16x8*)&Bs[n * 128 + ((g ^ (n & 7)) * 8)];
            }
            #pragma unroll
            for (int mi = 0; mi < 4; ++mi) {
                int r = wm * 64 + mi * 16 + lr;
                bf16x8 a = *(const bf16x8*)&As[r * 128 + ((g ^ (r & 7)) * 8)];
                #pragma unroll
                for (int ni = 0; ni < 4; ++ni)
                    acc[mi][ni] = __builtin_amdgcn_mfma_f32_16x16x32_bf16(a, b[ni], acc[mi][ni], 0, 0, 0);
            }
        }
        #pragma unroll
        for (int mi = 0; mi < 4; ++mi)
            #pragma unroll
            for (int ni = 0; ni < 4; ++ni)
                #pragma unroll
                for (int j = 0; j < 4; ++j) {
                    int gr = row0 + wm * 64 + mi * 16 + lg * 4 + j;
                    if (gr >= NN) continue;
                    int n = wn * 64 + ni * 16 + lr;
                    out[(size_t)gr * 128 + n] = (fp16_t)acc[mi][ni][j];
                }
    }
}

// ---------------------------------------------------------------- GAT1: packed-fp16, 8 lanes x 16ch per edge, 8 edges in flight
__global__ __launch_bounds__(256) void k_gat1(const int* __restrict__ perm,
                                              const fp16_t* __restrict__ xl1,
                                              const fp16_t* __restrict__ xr1,
                                              const fp16_t* __restrict__ skb,
                                              const int* __restrict__ offs,
                                              const int* __restrict__ deg,
                                              const int2* __restrict__ ep8,
                                              const float* __restrict__ att1,
                                              const float* __restrict__ we1,
                                              const float* __restrict__ b1,
                                              const float* __restrict__ skipb,
                                              bf16_t* __restrict__ hb,
                                              float* __restrict__ mattr) {
    int gid = (blockIdx.x * 256 + threadIdx.x) >> 6;
    if (gid >= NN) return;
    int v = perm[gid];
    int lane = threadIdx.x & 63;
    int sub = lane >> 3;       // 8 subgroups, 8 edges in flight
    int l = lane & 7;          // 8 lanes per edge, 16 ch per lane
    int c0 = l * 16;
    fp16x2 at2[8], we2[8], xr2v[8];
    {
        #pragma unroll
        for (int p = 0; p < 4; ++p) {
            float4 t = *(const float4*)(att1 + c0 + p * 4);
            at2[2 * p]     = fp16x2{(fp16_t)(t.x * LOG2E), (fp16_t)(t.y * LOG2E)};
            at2[2 * p + 1] = fp16x2{(fp16_t)(t.z * LOG2E), (fp16_t)(t.w * LOG2E)};
            float4 w = *(const float4*)(we1 + c0 + p * 4);
            we2[2 * p]     = fp16x2{(fp16_t)w.x, (fp16_t)w.y};
            we2[2 * p + 1] = fp16x2{(fp16_t)w.z, (fp16_t)w.w};
        }
        fp16x8 xlo = *(const fp16x8*)(xr1 + (size_t)v * 128 + c0);
        fp16x8 xhi = *(const fp16x8*)(xr1 + (size_t)v * 128 + c0 + 8);
        *(fp16x8*)&xr2v[0] = xlo;
        *(fp16x8*)&xr2v[4] = xhi;
    }
    float den = 0.f, easum = 0.f;
    fp16x2 n2[8] = {};
    int st = offs[v], dg = deg[v];
    int i = sub;
    int2 e0 = make_int2(0, 0), e1 = make_int2(0, 0), e2 = make_int2(0, 0);
    fp16x8 a0lo = {}, a0hi = {}, a1lo = {}, a1hi = {};
    if (i < dg) e0 = ep8[st + i];
    if (i + 8 < dg) e1 = ep8[st + i + 8];
    if (i + 16 < dg) e2 = ep8[st + i + 16];
    if (i < dg) {
        a0lo = *(const fp16x8*)(xl1 + (size_t)e0.x * 128 + c0);
        a0hi = *(const fp16x8*)(xl1 + (size_t)e0.x * 128 + c0 + 8);
    }
    if (i + 8 < dg) {
        a1lo = *(const fp16x8*)(xl1 + (size_t)e1.x * 128 + c0);
        a1hi = *(const fp16x8*)(xl1 + (size_t)e1.x * 128 + c0 + 8);
    }

#define GAT1_BODY                                                    \
    {                                                                \
        float ea_ = __int_as_float(e0.y);                            \
        easum += ea_;                                                \
        fp16x2 ea2 = bc2(ea_);                                       \
        fp16x2 xp[8];                                                \
        *(fp16x8*)&xp[0] = a0lo;                                     \
        *(fp16x8*)&xp[4] = a0hi;                                     \
        fp16x2 q2 = {};                                              \
        _Pragma("unroll")                                            \
        for (int j = 0; j < 8; ++j) {                                \
            fp16x2 w = xp[j] + (ea2 * we2[j] + xr2v[j]);             \
            w = leaky2(w);                                           \
            q2 = q2 + w * at2[j];                                    \
        }                                                            \
        float q = (float)q2[0] + (float)q2[1];                       \
        q += __shfl_xor(q, 1, 2);                                    \
        float ex = exp2f(q - QBIAS);                                 \
        den += ex;                                                   \
        fp16x2 ex2 = bc2(ex);                                        \
        _Pragma("unroll")                                            \
        for (int j = 0; j < 8; ++j) n2[j] = n2[j] + ex2 * xp[j];     \
        e0 = e1; e1 = e2; e2 = e3;                                   \
        a0lo = a1lo; a0hi = a1hi; a1lo = a2lo; a1hi = a2hi;          \
    }

    for (; i + 24 < dg; i += 8) {
        fp16x8 a2lo = *(const fp16x8*)(xl1 + (size_t)e2.x * 128 + c0);
        fp16x8 a2hi = *(const fp16x8*)(xl1 + (size_t)e2.x * 128 + c0 + 8);
        int2 e3 = ep8[st + i + 24];
        GAT1_BODY
    }
    for (; i < dg; i += 8) {
        fp16x8 a2lo = {}, a2hi = {};
        int2 e3 = make_int2(0, 0);
        if (i + 16 < dg) {
            a2lo = *(const fp16x8*)(xl1 + (size_t)e2.x * 128 + c0);
            a2hi = *(const fp16x8*)(xl1 + (size_t)e2.x * 128 + c0 + 8);
        }
        GAT1_BODY
    }
#undef GAT1_BODY

    // merge 8 subgroup states (plain sums)
    #pragma unroll
    for (int w_ = 8; w_ <= 32; w_ <<= 1) {
        den += __shfl_xor(den, w_, 64);
        easum += __shfl_xor(easum, w_, 64);
        #pragma unroll
        for (int j = 0; j < 8; ++j) n2[j] = n2[j] + shfl_p2(n2[j], w_);
    }
    // unpack n to f32
    float n[16];
    #pragma unroll
    for (int j = 0; j < 8; ++j) { n[2 * j] = (float)n2[j][0]; n[2 * j + 1] = (float)n2[j][1]; }
    // self loop (mean edge attr)
    float eav = easum / fmaxf((float)dg, 1.0f);
    if (lane == 0) mattr[v] = eav;
    fp16x2 xsp[8];
    {
        fp16x8 slo = *(const fp16x8*)(xl1 + (size_t)v * 128 + c0);
        fp16x8 shi = *(const fp16x8*)(xl1 + (size_t)v * 128 + c0 + 8);
        *(fp16x8*)&xsp[0] = slo;
        *(fp16x8*)&xsp[4] = shi;
    }
    {
        fp16x2 ea2 = bc2(eav);
        fp16x2 q2 = {};
        #pragma unroll
        for (int j = 0; j < 8; ++j) {
            fp16x2 w = xsp[j] + (ea2 * we2[j] + xr2v[j]);
            w = leaky2(w);
            q2 = q2 + w * at2[j];
        }
        float qs = (float)q2[0] + (float)q2[1];
        qs += __shfl_xor(qs, 1, 2);
        float ex = exp2f(qs - QBIAS);
        den += ex;
        #pragma unroll
        for (int j = 0; j < 8; ++j) {
            n[2 * j]     = fmaf(ex, (float)xsp[j][0], n[2 * j]);
            n[2 * j + 1] = fmaf(ex, (float)xsp[j][1], n[2 * j + 1]);
        }
    }
    if (sub == 0) {
        float inv = 1.0f / (den + 1e-16f);
        float bb[16], sv[16];
        #pragma unroll
        for (int p = 0; p < 4; ++p) {
            float4 t = *(const float4*)(b1 + c0 + p * 4);
            bb[4 * p] = t.x; bb[4 * p + 1] = t.y; bb[4 * p + 2] = t.z; bb[4 * p + 3] = t.w;
            float4 s = *(const float4*)(skipb + c0 + p * 4);
            sv[4 * p] = s.x; sv[4 * p + 1] = s.y; sv[4 * p + 2] = s.z; sv[4 * p + 3] = s.w;
        }
        fp16x8 sklo = *(const fp16x8*)(skb + (size_t)v * 128 + c0);
        fp16x8 skhi = *(const fp16x8*)(skb + (size_t)v * 128 + c0 + 8);
        bf16x8 r0, r1;
        #pragma unroll
        for (int j = 0; j < 8; ++j)
            r0[j] = (bf16_t)(n[j] * inv + bb[j] + (float)sklo[j] + sv[j]);
        #pragma unroll
        for (int j = 0; j < 8; ++j)
            r1[j] = (bf16_t)(n[8 + j] * inv + bb[8 + j] + (float)skhi[j] + sv[8 + j]);
        *(bf16x8*)(hb + (size_t)v * 128 + c0) = r0;
        *(bf16x8*)(hb + (size_t)v * 128 + c0 + 8) = r1;
    }
}

// ---------------------------------------------------------------- batchnorm stats
__global__ __launch_bounds__(256) void k_bnstats(const bf16_t* __restrict__ h,
                                                 float* __restrict__ bns,
                                                 float* __restrict__ bnq) {
    __shared__ float sS[16 * 128];
    __shared__ float sQ[16 * 128];
    int tid = threadIdx.x;
    int cg = tid & 15;
    int slot = tid >> 4;
    int c0 = cg * 8;
    float s[8] = {}, q[8] = {};
    for (int r = blockIdx.x * 16 + slot; r < NN; r += gridDim.x * 16) {
        bf16x8 v = *(const bf16x8*)&h[(size_t)r * 128 + c0];
        #pragma unroll
        for (int j = 0; j < 8; ++j) { float f = (float)v[j]; s[j] += f; q[j] += f * f; }
    }
    #pragma unroll
    for (int j = 0; j < 8; ++j) { sS[slot * 128 + c0 + j] = s[j]; sQ[slot * 128 + c0 + j] = q[j]; }
    __syncthreads();
    if (tid < 128) {
        float as = 0.f, aq = 0.f;
        #pragma unroll
        for (int k = 0; k < 16; ++k) { as += sS[k * 128 + tid]; aq += sQ[k * 128 + tid]; }
        atomicAdd(&bns[tid], as);
        atomicAdd(&bnq[tid], aq);
    }
}

__global__ void k_bnfinal(const float* __restrict__ bns, const float* __restrict__ bnq,
                          const float* __restrict__ g, const float* __restrict__ b,
                          float* __restrict__ scale, float* __restrict__ shift) {
    int c = threadIdx.x;
    if (c < 128) {
        float mu = bns[c] * (1.0f / NN);
        float var = bnq[c] * (1.0f / NN) - mu * mu;
        float rs = rsqrtf(var + 1e-5f);
        float a = rs * g[c];
        scale[c] = a;
        shift[c] = b[c] - mu * a;
    }
}

// ---------------------------------------------------------------- GEMM2 (MFMA): elu(bn(h_bf16)) @ Wb2T^T -> [xl2 fp16 | xr2 f32]
__global__ __launch_bounds__(256) void k_gemm2(const bf16_t* __restrict__ h,
                                               const float* __restrict__ scl,
                                               const float* __restrict__ shf,
                                               const bf16_t* __restrict__ Wb2T,
                                               fp16_t* __restrict__ xl2,
                                               float* __restrict__ xr2) {
    __shared__ bf16_t As[128 * 128];
    __shared__ bf16_t Bs[64 * 128];
    const int tid = threadIdx.x;
    const int row0 = blockIdx.x * 128;
    #pragma unroll
    for (int i = 0; i < 8; ++i) {
        int c = i * 256 + tid;
        int r = c >> 4, g = c & 15;
        int gr = row0 + r;
        bf16x8 v = {};
        if (gr < NN) {
            bf16x8 hv = *(const bf16x8*)(h + (size_t)gr * 128 + g * 8);
            float4 s0 = *(const float4*)(scl + g * 8);
            float4 s1 = *(const float4*)(scl + g * 8 + 4);
            float4 t0 = *(const float4*)(shf + g * 8);
            float4 t1 = *(const float4*)(shf + g * 8 + 4);
            float e[8];
            e[0] = (float)hv[0] * s0.x + t0.x; e[1] = (float)hv[1] * s0.y + t0.y;
            e[2] = (float)hv[2] * s0.z + t0.z; e[3] = (float)hv[3] * s0.w + t0.w;
            e[4] = (float)hv[4] * s1.x + t1.x; e[5] = (float)hv[5] * s1.y + t1.y;
            e[6] = (float)hv[6] * s1.z + t1.z; e[7] = (float)hv[7] * s1.w + t1.w;
            #pragma unroll
            for (int j = 0; j < 8; ++j) {
                float vv = e[j];
                vv = (vv > 0.f) ? vv : (__expf(vv) - 1.0f);
                v[j] = (bf16_t)vv;
            }
        }
        *(bf16x8*)&As[r * 128 + ((g ^ (r & 7)) * 8)] = v;
    }
    #pragma unroll
    for (int i = 0; i < 4; ++i) {
        int c = i * 256 + tid;
        int n = c >> 4, g = c & 15;
        bf16x8 v = *(const bf16x8*)(Wb2T + (size_t)n * 128 + g * 8);
        *(bf16x8*)&Bs[n * 128 + ((g ^ (n & 7)) * 8)] = v;
    }
    __syncthreads();

    const int wid = tid >> 6, lane = tid & 63;
    const int wm = wid >> 1, wn = wid & 1;
    const int lr = lane & 15, lg = lane >> 4;
    f32x4 acc[4][2] = {};
    #pragma unroll
    for (int ks = 0; ks < 4; ++ks) {
        int g = ks * 4 + lg;
        bf16x8 b0, b1;
        {
            int n = wn * 32 + lr;
            b0 = *(const bf16x8*)&Bs[n * 128 + ((g ^ (n & 7)) * 8)];
            n += 16;
            b1 = *(const bf16x8*)&Bs[n * 128 + ((g ^ (n & 7)) * 8)];
        }
        #pragma unroll
        for (int mi = 0; mi < 4; ++mi) {
            int r = wm * 64 + mi * 16 + lr;
            bf16x8 a = *(const bf16x8*)&As[r * 128 + ((g ^ (r & 7)) * 8)];
            acc[mi][0] = __builtin_amdgcn_mfma_f32_16x16x32_bf16(a, b0, acc[mi][0], 0, 0, 0);
            acc[mi][1] = __builtin_amdgcn_mfma_f32_16x16x32_bf16(a, b1, acc[mi][1], 0, 0, 0);
        }
    }
    #pragma unroll
    for (int mi = 0; mi < 4; ++mi)
        #pragma unroll
        for (int ni = 0; ni < 2; ++ni)
            #pragma unroll
            for (int j = 0; j < 4; ++j) {
                int gr = row0 + wm * 64 + mi * 16 + lg * 4 + j;
                if (gr >= NN) continue;
                int n = wn * 32 + ni * 16 + lr;
                float val = acc[mi][ni][j];
                if (n < 32) xl2[(size_t)gr * 32 + n] = (fp16_t)val;
                else xr2[(size_t)gr * 32 + (n - 32)] = val;
            }
}

// ---------------------------------------------------------------- GAT2: packed-fp16, 4 lanes x 8ch per edge, 16 edges in flight
__global__ __launch_bounds__(256) void k_gat2(const int* __restrict__ perm,
                                              const fp16_t* __restrict__ xl2,
                                              const float* __restrict__ xr2,
                                              const float* __restrict__ mattr,
                                              const int* __restrict__ offs,
                                              const int* __restrict__ deg,
                                              const int2* __restrict__ ep8,
                                              const float* __restrict__ att2,
                                              const float* __restrict__ we2_,
                                              const float* __restrict__ b2,
                                              float* __restrict__ h3,
                                              float* __restrict__ acsr,
                                              float* __restrict__ Inv,
                                              float* __restrict__ wout) {
    int gid = (blockIdx.x * 256 + threadIdx.x) >> 6;
    if (gid >= NN) return;
    int v = perm[gid];
    int lane = threadIdx.x & 63;
    int sub = lane >> 2;       // 16 subgroups, 16 edges in flight
    int l = lane & 3;          // 4 lanes per edge, 8 ch per lane
    int c0 = l * 8;
    fp16x2 at2[4], we2[4], xr2v[4];
    {
        float4 a0_ = *(const float4*)(att2 + c0);
        float4 a1_ = *(const float4*)(att2 + c0 + 4);
        at2[0] = fp16x2{(fp16_t)(a0_.x * LOG2E), (fp16_t)(a0_.y * LOG2E)};
        at2[1] = fp16x2{(fp16_t)(a0_.z * LOG2E), (fp16_t)(a0_.w * LOG2E)};
        at2[2] = fp16x2{(fp16_t)(a1_.x * LOG2E), (fp16_t)(a1_.y * LOG2E)};
        at2[3] = fp16x2{(fp16_t)(a1_.z * LOG2E), (fp16_t)(a1_.w * LOG2E)};
        float4 w0 = *(const float4*)(we2_ + c0);
        float4 w1 = *(const float4*)(we2_ + c0 + 4);
        we2[0] = fp16x2{(fp16_t)w0.x, (fp16_t)w0.y};
        we2[1] = fp16x2{(fp16_t)w0.z, (fp16_t)w0.w};
        we2[2] = fp16x2{(fp16_t)w1.x, (fp16_t)w1.y};
        we2[3] = fp16x2{(fp16_t)w1.z, (fp16_t)w1.w};
        float4 x0 = *(const float4*)(xr2 + (size_t)v * 32 + c0);
        float4 x1 = *(const float4*)(xr2 + (size_t)v * 32 + c0 + 4);
        xr2v[0] = fp16x2{(fp16_t)x0.x, (fp16_t)x0.y};
        xr2v[1] = fp16x2{(fp16_t)x0.z, (fp16_t)x0.w};
        xr2v[2] = fp16x2{(fp16_t)x1.x, (fp16_t)x1.y};
        xr2v[3] = fp16x2{(fp16_t)x1.z, (fp16_t)x1.w};
    }
    float den = 0.f;
    fp16x2 n2[4] = {};
    int st = offs[v], dg = deg[v];
    int i = sub;
    int2 e0 = make_int2(0, 0), e1 = make_int2(0, 0), e2 = make_int2(0, 0);
    fp16x8 a0 = {}, a1 = {};
    if (i < dg) e0 = ep8[st + i];
    if (i + 16 < dg) e1 = ep8[st + i + 16];
    if (i + 32 < dg) e2 = ep8[st + i + 32];
    if (i < dg) a0 = *(const fp16x8*)(xl2 + (size_t)e0.x * 32 + c0);
    if (i + 16 < dg) a1 = *(const fp16x8*)(xl2 + (size_t)e1.x * 32 + c0);

#define GAT2_BODY                                                    \
    {                                                                \
        float ea_ = __int_as_float(e0.y);                            \
        fp16x2 ea2 = bc2(ea_);                                       \
        const fp16x2* xp = (const fp16x2*)&a0;                       \
        fp16x2 q2 = {};                                              \
        _Pragma("unroll")                                            \
        for (int j = 0; j < 4; ++j) {                                \
            fp16x2 w = xp[j] + (ea2 * we2[j] + xr2v[j]);             \
            w = leaky2(w);                                           \
            q2 = q2 + w * at2[j];                                    \
        }                                                            \
        float q = (float)q2[0] + (float)q2[1];                       \
        q += __shfl_xor(q, 1, 4);                                    \
        q += __shfl_xor(q, 2, 4);                                    \
        if (l == 0) acsr[st + i] = q;                                \
        float ex = exp2f(q - QBIAS);                                 \
        den += ex;                                                   \
        fp16x2 ex2 = bc2(ex);                                        \
        _Pragma("unroll")                                            \
        for (int j = 0; j < 4; ++j) n2[j] = n2[j] + ex2 * xp[j];     \
        e0 = e1; e1 = e2; e2 = e3; a0 = a1; a1 = a2;                 \
    }

    for (; i + 48 < dg; i += 16) {
        fp16x8 a2 = *(const fp16x8*)(xl2 + (size_t)e2.x * 32 + c0);
        int2 e3 = ep8[st + i + 48];
        GAT2_BODY
    }
    for (; i < dg; i += 16) {
        fp16x8 a2 = {};
        int2 e3 = make_int2(0, 0);
        if (i + 32 < dg) a2 = *(const fp16x8*)(xl2 + (size_t)e2.x * 32 + c0);
        GAT2_BODY
    }
#undef GAT2_BODY

    // merge 16 subgroup states (plain sums)
    #pragma unroll
    for (int w_ = 4; w_ <= 32; w_ <<= 1) {
        den += __shfl_xor(den, w_, 64);
        #pragma unroll
        for (int j = 0; j < 4; ++j) n2[j] = n2[j] + shfl_p2(n2[j], w_);
    }
    float n[8];
    #pragma unroll
    for (int j = 0; j < 4; ++j) { n[2 * j] = (float)n2[j][0]; n[2 * j + 1] = (float)n2[j][1]; }
    // self loop
    float eav = mattr[v];
    fp16x8 sv = *(const fp16x8*)(xl2 + (size_t)v * 32 + c0);
    const fp16x2* xsp = (const fp16x2*)&sv;
    float qs;
    {
        fp16x2 ea2 = bc2(eav);
        fp16x2 q2 = {};
        #pragma unroll
        for (int j = 0; j < 4; ++j) {
            fp16x2 w = xsp[j] + (ea2 * we2[j] + xr2v[j]);
            w = leaky2(w);
            q2 = q2 + w * at2[j];
        }
        qs = (float)q2[0] + (float)q2[1];
        qs += __shfl_xor(qs, 1, 4);
        qs += __shfl_xor(qs, 2, 4);
        float ex = exp2f(qs - QBIAS);
        den += ex;
        #pragma unroll
        for (int j = 0; j < 4; ++j) {
            n[2 * j]     = fmaf(ex, (float)xsp[j][0], n[2 * j]);
            n[2 * j + 1] = fmaf(ex, (float)xsp[j][1], n[2 * j + 1]);
        }
    }
    float inv = 1.0f / (den + 1e-16f);
    if (lane == 0) {
        Inv[v] = inv;
        wout[EE + v] = exp2f(qs - QBIAS) * inv;
    }
    if (sub == 0) {
        float4 bb0 = *(const float4*)(b2 + c0);
        float4 bb1 = *(const float4*)(b2 + c0 + 4);
        float b_[8] = {bb0.x, bb0.y, bb0.z, bb0.w, bb1.x, bb1.y, bb1.z, bb1.w};
        float r[8];
        #pragma unroll
        for (int j = 0; j < 8; ++j) {
            float o = n[j] * inv + b_[j];
            r[j] = (o > 0.f) ? o : (__expf(o) - 1.0f);
        }
        *(float4*)(h3 + (size_t)v * 32 + c0) = make_float4(r[0], r[1], r[2], r[3]);
        *(float4*)(h3 + (size_t)v * 32 + c0 + 4) = make_float4(r[4], r[5], r[6], r[7]);
    }
}

// ---------------------------------------------------------------- finalize attention weights (original edge order)
__global__ __launch_bounds__(256) void k_wfinal(const int* __restrict__ ei,
                                                const int* __restrict__ offs,
                                                const int* __restrict__ slot,
                                                const float* __restrict__ acsr,
                                                const float* __restrict__ Inv,
                                                float* __restrict__ wout) {
    int e = blockIdx.x * 256 + threadIdx.x;
    if (e >= EE) return;
    int d = ei[EE + e];
    float al = acsr[offs[d] + slot[e]];
    wout[e] = exp2f(al - QBIAS) * Inv[d];
}

// ---------------------------------------------------------------- heads
__global__ __launch_bounds__(256) void k_head(const float* __restrict__ h3,
                                              const float* __restrict__ fc1W,
                                              const float* __restrict__ fc1b,
                                              const float* __restrict__ Wc,
                                              const float* __restrict__ bc,
                                              const float* __restrict__ Wt,
                                              const float* __restrict__ bt,
                                              float* __restrict__ outp) {
    __shared__ float sW1[32 * 32];
    __shared__ float sWc[32 * NCLONE];
    __shared__ float sWt[32 * NTYPE];
    __shared__ float sb1[32], sbc[NCLONE], sbt[NTYPE];
    int tid = threadIdx.x;
    for (int i = tid; i < 1024; i += 256) sW1[i] = fc1W[i];
    for (int i = tid; i < 32 * NCLONE; i += 256) sWc[i] = Wc[i];
    for (int i = tid; i < 32 * NTYPE; i += 256) sWt[i] = Wt[i];
    if (tid < 32) sb1[tid] = fc1b[tid];
    if (tid < NCLONE) sbc[tid] = bc[tid];
    if (tid < NTYPE) sbt[tid] = bt[tid];
    __syncthreads();
    int g = tid >> 5, l = tid & 31;
    int v = blockIdx.x * 8 + g;
    if (v >= NN) return;
    float x = h3[(size_t)v * CCH + l];
    float acc = sb1[l];
    #pragma unroll
    for (int c = 0; c < 32; ++c) {
        float xc = __shfl(x, c, 32);
        acc += xc * sW1[c * 32 + l];
    }
    float hl = fmaxf(acc, 0.0f);
    float at = (l < NTYPE) ? sbt[l] : 0.0f;
    float ac = (l < NCLONE) ? sbc[l] : 0.0f;
    #pragma unroll
    for (int c = 0; c < 32; ++c) {
        float hc = __shfl(hl, c, 32);
        float wt_ = (l < NTYPE) ? sWt[c * NTYPE + l] : 0.0f;
        float wc_ = (l < NCLONE) ? sWc[c * NCLONE + l] : 0.0f;
        at += hc * wt_;
        ac += hc * wc_;
    }
    float vt = (l < NTYPE) ? at : -INFINITY;
    float mt = vt;
    mt = fmaxf(mt, __shfl_xor(mt, 16, 32));
    mt = fmaxf(mt, __shfl_xor(mt, 8, 32));
    mt = fmaxf(mt, __shfl_xor(mt, 4, 32));
    mt = fmaxf(mt, __shfl_xor(mt, 2, 32));
    mt = fmaxf(mt, __shfl_xor(mt, 1, 32));
    float et = __expf(vt - mt);
    float stt = et;
    stt += __shfl_xor(stt, 16, 32);
    stt += __shfl_xor(stt, 8, 32);
    stt += __shfl_xor(stt, 4, 32);
    stt += __shfl_xor(stt, 2, 32);
    stt += __shfl_xor(stt, 1, 32);
    float lt = vt - mt - logf(stt);
    float vc = (l < NCLONE) ? ac : -INFINITY;
    float mc = vc;
    mc = fmaxf(mc, __shfl_xor(mc, 16, 32));
    mc = fmaxf(mc, __shfl_xor(mc, 8, 32));
    mc = fmaxf(mc, __shfl_xor(mc, 4, 32));
    mc = fmaxf(mc, __shfl_xor(mc, 2, 32));
    mc = fmaxf(mc, __shfl_xor(mc, 1, 32));
    float ec = __expf(vc - mc);
    float sc = ec;
    sc += __shfl_xor(sc, 16, 32);
    sc += __shfl_xor(sc, 8, 32);
    sc += __shfl_xor(sc, 4, 32);
    sc += __shfl_xor(sc, 2, 32);
    sc += __shfl_xor(sc, 1, 32);
    float lc = vc - mc - logf(sc);
    size_t ob = (size_t)v * 48;
    if (l < NCLONE) outp[ob + l] = lc;
    if (l < NTYPE) outp[ob + NCLONE + l] = lt;
}

// ---------------------------------------------------------------- launcher
extern "C" void kernel_launch(void* const* d_in, const int* in_sizes, int n_in,
                              void* d_out, int out_size, void* d_ws, size_t ws_size,
                              hipStream_t stream) {
    const float* x     = (const float*)d_in[0];
    const int*   ei    = (const int*)d_in[1];
    const float* ea    = (const float*)d_in[2];
    const float* Wl1   = (const float*)d_in[3];
    const float* Wr1   = (const float*)d_in[4];
    const float* We1   = (const float*)d_in[5];
    const float* att1  = (const float*)d_in[6];
    const float* b1    = (const float*)d_in[7];
    const float* skipW = (const float*)d_in[8];
    const float* skipb = (const float*)d_in[9];
    const float* bng   = (const float*)d_in[10];
    const float* bnb   = (const float*)d_in[11];
    const float* Wl2   = (const float*)d_in[12];
    const float* Wr2   = (const float*)d_in[13];
    const float* We2   = (const float*)d_in[14];
    const float* att2  = (const float*)d_in[15];
    const float* b2    = (const float*)d_in[16];
    const float* fc1W  = (const float*)d_in[17];
    const float* fc1b  = (const float*)d_in[18];
    const float* Wc    = (const float*)d_in[19];
    const float* bc    = (const float*)d_in[20];
    const float* Wt    = (const float*)d_in[21];
    const float* bt    = (const float*)d_in[22];
    float* out = (float*)d_out;
    float* wout = out + (size_t)NN * 48;

    const size_t NF = (size_t)NN * FIN;   // 12.8M elems
    char* w = (char*)d_ws;
    fp16_t* xl1h = (fp16_t*)w;  w += NF * 2;
    fp16_t* xr1h = (fp16_t*)w;  w += NF * 2;
    fp16_t* skb  = (fp16_t*)w;  w += NF * 2;
    bf16_t* hb   = (bf16_t*)w;  w += NF * 2;
    int2*   ep8  = (int2*)w;    w += (size_t)EE * 8;
    float*  acsr = (float*)w;   w += (size_t)EE * 4;
    int*    slot = (int*)w;     w += (size_t)EE * 4;
    int* deg   = (int*)w;   w += (size_t)NN * 4;
    int* offs  = (int*)w;   w += (size_t)NN * 4;
    float* mattr = (float*)w; w += (size_t)NN * 4;
    float* Inv   = (float*)w; w += (size_t)NN * 4;
    int*   perm  = (int*)w;   w += (size_t)NN * 4;
    int*   bsum  = (int*)w;   w += 64 * 4;
    float* bns   = (float*)w; w += 128 * 4;
    float* bnq   = (float*)w; w += 128 * 4;
    int*   hist  = (int*)w;   w += NBIN * 4;
    int*   binpos= (int*)w;   w += NBIN * 4;
    float* scl   = (float*)w; w += 128 * 4;
    float* shf   = (float*)w; w += 128 * 4;
    bf16_t* WbT  = (bf16_t*)w; w += 384 * 128 * 2;
    bf16_t* Wb2T = (bf16_t*)w; w += 64 * 128 * 2;
    // aliases into dead regions (after gat1):
    fp16_t* xl2h = xl1h;              // 6.4 MB
    float*  xr2  = (float*)xr1h;      // 12.8 MB
    float*  h3   = (float*)skb;       // 12.8 MB

    hipMemsetAsync(deg, 0, (size_t)NN * sizeof(int), stream);
    hipMemsetAsync(bns, 0, (256 + NBIN) * sizeof(float), stream);   // bns + bnq + hist

    k_wcvt<<<224, 256, 0, stream>>>(Wl1, Wr1, skipW, Wl2, Wr2, WbT, Wb2T);

    k_deg<<<6250, 256, 0, stream>>>(ei, deg, slot);
    k_hist<<<391, 256, 0, stream>>>(deg, hist);
    k_bscan<<<1, 64, 0, stream>>>(hist, binpos);
    k_scat<<<391, 256, 0, stream>>>(deg, binpos, perm);
    k_scan1<<<SCAN_B, 256, 0, stream>>>(deg, offs, bsum);
    k_scan2<<<1, 64, 0, stream>>>(bsum);
    k_scan3<<<391, 256, 0, stream>>>(offs, bsum);
    k_fill<<<6250, 256, 0, stream>>>(ei, ea, offs, slot, ep8);

    k_gemm1<<<782, 256, 0, stream>>>(x, WbT, xl1h, xr1h, skb);
    k_gat1<<<25000, 256, 0, stream>>>(perm, xl1h, xr1h, skb, offs, deg, ep8,
                                      att1, We1, b1, skipb, hb, mattr);
    k_bnstats<<<128, 256, 0, stream>>>(hb, bns, bnq);
    k_bnfinal<<<1, 128, 0, stream>>>(bns, bnq, bng, bnb, scl, shf);
    k_gemm2<<<782, 256, 0, stream>>>(hb, scl, shf, Wb2T, xl2h, xr2);
    k_gat2<<<25000, 256, 0, stream>>>(perm, xl2h, xr2, mattr, offs, deg, ep8,
                                      att2, We2, b2, h3, acsr, Inv, wout);
    k_wfinal<<<6250, 256, 0, stream>>>(ei, offs, slot, acsr, Inv, wout);
    k_head<<<12500, 256, 0, stream>>>(h3, fc1W, fc1b, Wc, bc, Wt, bt, out);
}

// Round 12
// 425.285 us; speedup vs baseline: 1.1622x; 1.1622x over previous
//
#include <hip/hip_runtime.h>
#include <math.h>

// Problem constants
#define NN 100000
#define EE 1600000
#define FIN 128
#define HCH 128     // H*C for gat1
#define CCH 32      // C
#define NCLONE 19
#define NTYPE 29
#define ETOT (EE + NN)
#define SCAN_B 49   // ceil(NN / 2048)
#define NBIN 128
#define LOG2E 1.4426950408889634f
#define QBIAS 5.0f

typedef __bf16 bf16_t;
typedef bf16_t bf16x8 __attribute__((ext_vector_type(8)));
typedef _Float16 fp16_t;
typedef fp16_t fp16x2 __attribute__((ext_vector_type(2)));
typedef fp16_t fp16x4 __attribute__((ext_vector_type(4)));
typedef fp16_t fp16x8 __attribute__((ext_vector_type(8)));
typedef float f32x4 __attribute__((ext_vector_type(4)));

static __device__ __forceinline__ fp16x2 shfl_p2(fp16x2 v, int mask) {
    float f = __shfl_xor(__builtin_bit_cast(float, v), mask, 64);
    return __builtin_bit_cast(fp16x2, f);
}
static __device__ __forceinline__ fp16x2 bc2(float f) {
    fp16_t h = (fp16_t)f;
    fp16x2 r = {h, h};
    return r;
}
// leaky_relu(w, 0.2) == 0.6*w + 0.4*|w|   (exact for both signs)
static __device__ __forceinline__ fp16x2 leaky2(fp16x2 w) {
    unsigned u = __builtin_bit_cast(unsigned, w) & 0x7FFF7FFFu;
    fp16x2 aw = __builtin_bit_cast(fp16x2, u);
    const fp16x2 c06 = {(fp16_t)0.6f, (fp16_t)0.6f};
    const fp16x2 c04 = {(fp16_t)0.4f, (fp16_t)0.4f};
    return c06 * w + c04 * aw;
}

// ---------------------------------------------------------------- weight conversion
__global__ __launch_bounds__(256) void k_wcvt(const float* __restrict__ Wl1,
                                              const float* __restrict__ Wr1,
                                              const float* __restrict__ Ws,
                                              const float* __restrict__ Wl2,
                                              const float* __restrict__ Wr2,
                                              bf16_t* __restrict__ WbT,
                                              bf16_t* __restrict__ Wb2T) {
    int t = blockIdx.x * 256 + threadIdx.x;
    if (t < 384 * 128) {
        int n = t >> 7, k = t & 127;
        const float* W = (n < 128) ? Wl1 : ((n < 256) ? Wr1 : Ws);
        WbT[t] = (bf16_t)W[k * 128 + (n & 127)];
    } else if (t < 384 * 128 + 64 * 128) {
        int u = t - 384 * 128;
        int n = u >> 7, k = u & 127;
        const float* W = (n < 32) ? Wl2 : Wr2;
        Wb2T[u] = (bf16_t)W[k * 32 + (n & 31)];
    }
}

// ---------------------------------------------------------------- degree + slot
__global__ __launch_bounds__(256) void k_deg(const int* __restrict__ ei,
                                             int* __restrict__ deg,
                                             int* __restrict__ slot) {
    int e = blockIdx.x * 256 + threadIdx.x;
    if (e < EE) {
        int d = ei[EE + e];
        slot[e] = atomicAdd(&deg[d], 1);
    }
}

// ---------------------------------------------------------------- exclusive scan of deg + degree histogram (fused)
__global__ __launch_bounds__(256) void k_scan1(const int* __restrict__ deg,
                                               int* __restrict__ offs,
                                               int* __restrict__ bsum,
                                               int* __restrict__ hist) {
    __shared__ int tsum[256];
    __shared__ int lh[NBIN];
    int b = blockIdx.x, tid = threadIdx.x;
    if (tid < NBIN) lh[tid] = 0;
    int base = b * 2048;
    int loc[8], dv[8];
    int s = 0;
    #pragma unroll
    for (int i = 0; i < 8; ++i) {
        int idx = base + tid * 8 + i;
        int d = (idx < NN) ? deg[idx] : 0;
        dv[i] = (idx < NN) ? d : -1;
        loc[i] = s; s += d;
    }
    tsum[tid] = s;
    __syncthreads();
    #pragma unroll
    for (int i = 0; i < 8; ++i)
        if (dv[i] >= 0) atomicAdd(&lh[min(dv[i], NBIN - 1)], 1);
    for (int off = 1; off < 256; off <<= 1) {
        int v = (tid >= off) ? tsum[tid - off] : 0;
        __syncthreads();
        tsum[tid] += v;
        __syncthreads();
    }
    int texcl = tsum[tid] - s;
    #pragma unroll
    for (int i = 0; i < 8; ++i) {
        int idx = base + tid * 8 + i;
        if (idx < NN) offs[idx] = texcl + loc[i];
    }
    if (tid == 255) bsum[b] = tsum[255];
    __syncthreads();
    if (tid < NBIN && lh[tid]) atomicAdd(&hist[tid], lh[tid]);
}

// serial: bsum prefix + descending-degree binpos
__global__ void k_serial(int* __restrict__ bsum,
                         const int* __restrict__ hist,
                         int* __restrict__ binpos) {
    if (threadIdx.x == 0) {
        int run = 0;
        for (int i = 0; i < SCAN_B; ++i) { int t = bsum[i]; bsum[i] = run; run += t; }
        run = 0;
        for (int b = NBIN - 1; b >= 0; --b) { binpos[b] = run; run += hist[b]; }
    }
}

__global__ __launch_bounds__(256) void k_scan3(int* __restrict__ offs,
                                               const int* __restrict__ bsum) {
    int i = blockIdx.x * 256 + threadIdx.x;
    if (i < NN) offs[i] += bsum[i >> 11];
}

__global__ __launch_bounds__(256) void k_scat(const int* __restrict__ deg,
                                              int* __restrict__ binpos,
                                              int* __restrict__ perm) {
    __shared__ int lcnt[NBIN];
    __shared__ int lbase[NBIN];
    int tid = threadIdx.x;
    if (tid < NBIN) lcnt[tid] = 0;
    __syncthreads();
    int v = blockIdx.x * 256 + tid;
    int b = 0, r = 0;
    bool ok = (v < NN);
    if (ok) {
        b = min(deg[v], NBIN - 1);
        r = atomicAdd(&lcnt[b], 1);
    }
    __syncthreads();
    if (tid < NBIN && lcnt[tid]) lbase[tid] = atomicAdd(&binpos[tid], lcnt[tid]);
    __syncthreads();
    if (ok) perm[lbase[b] + r] = v;
}

// ---------------------------------------------------------------- CSR fill (atomic-free)
__global__ __launch_bounds__(256) void k_fill(const int* __restrict__ ei,
                                              const float* __restrict__ ea,
                                              const int* __restrict__ offs,
                                              const int* __restrict__ slot,
                                              int2* __restrict__ ep8) {
    int e = blockIdx.x * 256 + threadIdx.x;
    if (e < EE) {
        int d = ei[EE + e];
        int pos = offs[d] + slot[e];
        ep8[pos] = make_int2(ei[e], __float_as_int(ea[e]));
    }
}

// ---------------------------------------------------------------- GEMM1 (MFMA): x(f32) @ WbT^T -> [xl1|xr1|skb] (fp16)
__global__ __launch_bounds__(256) void k_gemm1(const float* __restrict__ x,
                                               const bf16_t* __restrict__ WbT,
                                               fp16_t* __restrict__ xl,
                                               fp16_t* __restrict__ xr,
                                               fp16_t* __restrict__ sk) {
    __shared__ bf16_t As[128 * 128];
    __shared__ bf16_t Bs[128 * 128];
    const int tid = threadIdx.x;
    const int row0 = blockIdx.x * 128;
    #pragma unroll
    for (int i = 0; i < 8; ++i) {
        int c = i * 256 + tid;
        int r = c >> 4, g = c & 15;
        int gr = row0 + r;
        bf16x8 v = {};
        if (gr < NN) {
            float4 f0 = *(const float4*)(x + (size_t)gr * 128 + g * 8);
            float4 f1 = *(const float4*)(x + (size_t)gr * 128 + g * 8 + 4);
            v[0] = (bf16_t)f0.x; v[1] = (bf16_t)f0.y; v[2] = (bf16_t)f0.z; v[3] = (bf16_t)f0.w;
            v[4] = (bf16_t)f1.x; v[5] = (bf16_t)f1.y; v[6] = (bf16_t)f1.z; v[7] = (bf16_t)f1.w;
        }
        *(bf16x8*)&As[r * 128 + ((g ^ (r & 7)) * 8)] = v;
    }

    const int wid = tid >> 6, lane = tid & 63;
    const int wm = wid >> 1, wn = wid & 1;
    const int lr = lane & 15, lg = lane >> 4;

    for (int chunk = 0; chunk < 3; ++chunk) {
        const int col0 = chunk * 128;
        fp16_t* __restrict__ out = (chunk == 0) ? xl : ((chunk == 1) ? xr : sk);
        __syncthreads();
        #pragma unroll
        for (int i = 0; i < 8; ++i) {
            int c = i * 256 + tid;
            int n = c >> 4, g = c & 15;
            bf16x8 v = *(const bf16x8*)(WbT + (size_t)(col0 + n) * 128 + g * 8);
            *(bf16x8*)&Bs[n * 128 + ((g ^ (n & 7)) * 8)] = v;
        }
        __syncthreads();

        f32x4 acc[4][4] = {};
        #pragma unroll
        for (int ks = 0; ks < 4; ++ks) {
            int g = ks * 4 + lg;
            bf16x8 b[4];
            #pragma unroll
            for (int ni = 0; ni < 4; ++ni) {
                int n = wn * 64 + ni * 16 + lr;
                b[ni] = *(const bf16x8*)&Bs[n * 128 + ((g ^ (n & 7)) * 8)];
            }
            #pragma unroll
            for (int mi = 0; mi < 4; ++mi) {
                int r = wm * 64 + mi * 16 + lr;
                bf16x8 a = *(const bf16x8*)&As[r * 128 + ((g ^ (r & 7)) * 8)];
                #pragma unroll
                for (int ni = 0; ni < 4; ++ni)
                    acc[mi][ni] = __builtin_amdgcn_mfma_f32_16x16x32_bf16(a, b[ni], acc[mi][ni], 0, 0, 0);
            }
        }
        #pragma unroll
        for (int mi = 0; mi < 4; ++mi)
            #pragma unroll
            for (int ni = 0; ni < 4; ++ni)
                #pragma unroll
                for (int j = 0; j < 4; ++j) {
                    int gr = row0 + wm * 64 + mi * 16 + lg * 4 + j;
                    if (gr >= NN) continue;
                    int n = wn * 64 + ni * 16 + lr;
                    out[(size_t)gr * 128 + n] = (fp16_t)acc[mi][ni][j];
                }
    }
}

// ---------------------------------------------------------------- GAT1: packed-fp16, 16 lanes x 8ch per edge, 4 subgroups, depth-3
__global__ __launch_bounds__(256) void k_gat1(const int* __restrict__ perm,
                                              const fp16_t* __restrict__ xl1,
                                              const fp16_t* __restrict__ xr1,
                                              const fp16_t* __restrict__ skb,
                                              const int* __restrict__ offs,
                                              const int* __restrict__ deg,
                                              const int2* __restrict__ ep8,
                                              const float* __restrict__ att1,
                                              const float* __restrict__ we1,
                                              const float* __restrict__ b1,
                                              const float* __restrict__ skipb,
                                              bf16_t* __restrict__ hb,
                                              float* __restrict__ mattr) {
    int gid = (blockIdx.x * 256 + threadIdx.x) >> 6;
    if (gid >= NN) return;
    int v = perm[gid];
    int lane = threadIdx.x & 63;
    int sub = lane >> 4;
    int l = lane & 15;
    int c0 = l * 8;
    fp16x2 at2[4], we2[4], xr2v[4];
    {
        float4 t0 = *(const float4*)(att1 + c0);
        float4 t1 = *(const float4*)(att1 + c0 + 4);
        at2[0] = fp16x2{(fp16_t)(t0.x * LOG2E), (fp16_t)(t0.y * LOG2E)};
        at2[1] = fp16x2{(fp16_t)(t0.z * LOG2E), (fp16_t)(t0.w * LOG2E)};
        at2[2] = fp16x2{(fp16_t)(t1.x * LOG2E), (fp16_t)(t1.y * LOG2E)};
        at2[3] = fp16x2{(fp16_t)(t1.z * LOG2E), (fp16_t)(t1.w * LOG2E)};
        float4 w0 = *(const float4*)(we1 + c0);
        float4 w1 = *(const float4*)(we1 + c0 + 4);
        we2[0] = fp16x2{(fp16_t)w0.x, (fp16_t)w0.y};
        we2[1] = fp16x2{(fp16_t)w0.z, (fp16_t)w0.w};
        we2[2] = fp16x2{(fp16_t)w1.x, (fp16_t)w1.y};
        we2[3] = fp16x2{(fp16_t)w1.z, (fp16_t)w1.w};
        fp16x8 xrv = *(const fp16x8*)(xr1 + (size_t)v * 128 + c0);
        const fp16x2* xp = (const fp16x2*)&xrv;
        xr2v[0] = xp[0]; xr2v[1] = xp[1]; xr2v[2] = xp[2]; xr2v[3] = xp[3];
    }
    float den = 0.f, easum = 0.f;
    fp16x2 n2[4] = {};
    int st = offs[v], dg = deg[v];
    int i = sub;
    int2 e0 = make_int2(0, 0), e1 = make_int2(0, 0), e2 = make_int2(0, 0);
    fp16x8 a0 = {}, a1 = {};
    if (i < dg) e0 = ep8[st + i];
    if (i + 4 < dg) e1 = ep8[st + i + 4];
    if (i + 8 < dg) e2 = ep8[st + i + 8];
    if (i < dg) a0 = *(const fp16x8*)(xl1 + (size_t)e0.x * 128 + c0);
    if (i + 4 < dg) a1 = *(const fp16x8*)(xl1 + (size_t)e1.x * 128 + c0);

#define GAT1_BODY                                                    \
    {                                                                \
        float ea_ = __int_as_float(e0.y);                            \
        easum += ea_;                                                \
        fp16x2 ea2 = bc2(ea_);                                       \
        const fp16x2* xp = (const fp16x2*)&a0;                       \
        fp16x2 q2 = {};                                              \
        _Pragma("unroll")                                            \
        for (int j = 0; j < 4; ++j) {                                \
            fp16x2 w = xp[j] + (ea2 * we2[j] + xr2v[j]);             \
            w = leaky2(w);                                           \
            q2 = q2 + w * at2[j];                                    \
        }                                                            \
        float q = (float)q2[0] + (float)q2[1];                       \
        q += __shfl_xor(q, 1, 4);                                    \
        q += __shfl_xor(q, 2, 4);                                    \
        float ex = exp2f(q - QBIAS);                                 \
        den += ex;                                                   \
        fp16x2 ex2 = bc2(ex);                                        \
        _Pragma("unroll")                                            \
        for (int j = 0; j < 4; ++j) n2[j] = n2[j] + ex2 * xp[j];     \
        e0 = e1; e1 = e2; e2 = e3; a0 = a1; a1 = a2;                 \
    }

    #pragma unroll 2
    for (; i + 12 < dg; i += 4) {
        fp16x8 a2 = *(const fp16x8*)(xl1 + (size_t)e2.x * 128 + c0);
        int2 e3 = ep8[st + i + 12];
        GAT1_BODY
    }
    for (; i < dg; i += 4) {
        fp16x8 a2 = {};
        int2 e3 = make_int2(0, 0);
        if (i + 8 < dg) a2 = *(const fp16x8*)(xl1 + (size_t)e2.x * 128 + c0);
        GAT1_BODY
    }
#undef GAT1_BODY

    // merge 4 subgroup states (plain sums)
    #pragma unroll
    for (int w_ = 16; w_ <= 32; w_ <<= 1) {
        den += __shfl_xor(den, w_, 64);
        easum += __shfl_xor(easum, w_, 64);
        #pragma unroll
        for (int j = 0; j < 4; ++j) n2[j] = n2[j] + shfl_p2(n2[j], w_);
    }
    // unpack n to f32
    float n[8];
    #pragma unroll
    for (int j = 0; j < 4; ++j) { n[2 * j] = (float)n2[j][0]; n[2 * j + 1] = (float)n2[j][1]; }
    // self loop (mean edge attr)
    float eav = easum / fmaxf((float)dg, 1.0f);
    if (lane == 0) mattr[v] = eav;
    fp16x8 svv = *(const fp16x8*)(xl1 + (size_t)v * 128 + c0);
    const fp16x2* xsp = (const fp16x2*)&svv;
    {
        fp16x2 ea2 = bc2(eav);
        fp16x2 q2 = {};
        #pragma unroll
        for (int j = 0; j < 4; ++j) {
            fp16x2 w = xsp[j] + (ea2 * we2[j] + xr2v[j]);
            w = leaky2(w);
            q2 = q2 + w * at2[j];
        }
        float qs = (float)q2[0] + (float)q2[1];
        qs += __shfl_xor(qs, 1, 4);
        qs += __shfl_xor(qs, 2, 4);
        float ex = exp2f(qs - QBIAS);
        den += ex;
        #pragma unroll
        for (int j = 0; j < 4; ++j) {
            n[2 * j]     = fmaf(ex, (float)xsp[j][0], n[2 * j]);
            n[2 * j + 1] = fmaf(ex, (float)xsp[j][1], n[2 * j + 1]);
        }
    }
    if (sub == 0) {
        float inv = 1.0f / (den + 1e-16f);
        float4 bb0 = *(const float4*)(b1 + c0);
        float4 bb1 = *(const float4*)(b1 + c0 + 4);
        float4 sb0 = *(const float4*)(skipb + c0);
        float4 sb1 = *(const float4*)(skipb + c0 + 4);
        fp16x8 skv = *(const fp16x8*)(skb + (size_t)v * 128 + c0);
        float bb[8] = {bb0.x, bb0.y, bb0.z, bb0.w, bb1.x, bb1.y, bb1.z, bb1.w};
        float sv[8] = {sb0.x, sb0.y, sb0.z, sb0.w, sb1.x, sb1.y, sb1.z, sb1.w};
        bf16x8 r;
        #pragma unroll
        for (int j = 0; j < 8; ++j)
            r[j] = (bf16_t)(n[j] * inv + bb[j] + (float)skv[j] + sv[j]);
        *(bf16x8*)(hb + (size_t)v * 128 + c0) = r;
    }
}

// ---------------------------------------------------------------- batchnorm stats
__global__ __launch_bounds__(256) void k_bnstats(const bf16_t* __restrict__ h,
                                                 float* __restrict__ bns,
                                                 float* __restrict__ bnq) {
    __shared__ float sS[16 * 128];
    __shared__ float sQ[16 * 128];
    int tid = threadIdx.x;
    int cg = tid & 15;
    int slot = tid >> 4;
    int c0 = cg * 8;
    float s[8] = {}, q[8] = {};
    for (int r = blockIdx.x * 16 + slot; r < NN; r += gridDim.x * 16) {
        bf16x8 v = *(const bf16x8*)&h[(size_t)r * 128 + c0];
        #pragma unroll
        for (int j = 0; j < 8; ++j) { float f = (float)v[j]; s[j] += f; q[j] += f * f; }
    }
    #pragma unroll
    for (int j = 0; j < 8; ++j) { sS[slot * 128 + c0 + j] = s[j]; sQ[slot * 128 + c0 + j] = q[j]; }
    __syncthreads();
    if (tid < 128) {
        float as = 0.f, aq = 0.f;
        #pragma unroll
        for (int k = 0; k < 16; ++k) { as += sS[k * 128 + tid]; aq += sQ[k * 128 + tid]; }
        atomicAdd(&bns[tid], as);
        atomicAdd(&bnq[tid], aq);
    }
}

__global__ void k_bnfinal(const float* __restrict__ bns, const float* __restrict__ bnq,
                          const float* __restrict__ g, const float* __restrict__ b,
                          float* __restrict__ scale, float* __restrict__ shift) {
    int c = threadIdx.x;
    if (c < 128) {
        float mu = bns[c] * (1.0f / NN);
        float var = bnq[c] * (1.0f / NN) - mu * mu;
        float rs = rsqrtf(var + 1e-5f);
        float a = rs * g[c];
        scale[c] = a;
        shift[c] = b[c] - mu * a;
    }
}

// ---------------------------------------------------------------- GEMM2 (MFMA): elu(bn(h_bf16)) @ Wb2T^T -> [xl2 fp16 | xr2 f32]
__global__ __launch_bounds__(256) void k_gemm2(const bf16_t* __restrict__ h,
                                               const float* __restrict__ scl,
                                               const float* __restrict__ shf,
                                               const bf16_t* __restrict__ Wb2T,
                                               fp16_t* __restrict__ xl2,
                                               float* __restrict__ xr2) {
    __shared__ bf16_t As[128 * 128];
    __shared__ bf16_t Bs[64 * 128];
    const int tid = threadIdx.x;
    const int row0 = blockIdx.x * 128;
    #pragma unroll
    for (int i = 0; i < 8; ++i) {
        int c = i * 256 + tid;
        int r = c >> 4, g = c & 15;
        int gr = row0 + r;
        bf16x8 v = {};
        if (gr < NN) {
            bf16x8 hv = *(const bf16x8*)(h + (size_t)gr * 128 + g * 8);
            float4 s0 = *(const float4*)(scl + g * 8);
            float4 s1 = *(const float4*)(scl + g * 8 + 4);
            float4 t0 = *(const float4*)(shf + g * 8);
            float4 t1 = *(const float4*)(shf + g * 8 + 4);
            float e[8];
            e[0] = (float)hv[0] * s0.x + t0.x; e[1] = (float)hv[1] * s0.y + t0.y;
            e[2] = (float)hv[2] * s0.z + t0.z; e[3] = (float)hv[3] * s0.w + t0.w;
            e[4] = (float)hv[4] * s1.x + t1.x; e[5] = (float)hv[5] * s1.y + t1.y;
            e[6] = (float)hv[6] * s1.z + t1.z; e[7] = (float)hv[7] * s1.w + t1.w;
            #pragma unroll
            for (int j = 0; j < 8; ++j) {
                float vv = e[j];
                vv = (vv > 0.f) ? vv : (__expf(vv) - 1.0f);
                v[j] = (bf16_t)vv;
            }
        }
        *(bf16x8*)&As[r * 128 + ((g ^ (r & 7)) * 8)] = v;
    }
    #pragma unroll
    for (int i = 0; i < 4; ++i) {
        int c = i * 256 + tid;
        int n = c >> 4, g = c & 15;
        bf16x8 v = *(const bf16x8*)(Wb2T + (size_t)n * 128 + g * 8);
        *(bf16x8*)&Bs[n * 128 + ((g ^ (n & 7)) * 8)] = v;
    }
    __syncthreads();

    const int wid = tid >> 6, lane = tid & 63;
    const int wm = wid >> 1, wn = wid & 1;
    const int lr = lane & 15, lg = lane >> 4;
    f32x4 acc[4][2] = {};
    #pragma unroll
    for (int ks = 0; ks < 4; ++ks) {
        int g = ks * 4 + lg;
        bf16x8 b0, b1;
        {
            int n = wn * 32 + lr;
            b0 = *(const bf16x8*)&Bs[n * 128 + ((g ^ (n & 7)) * 8)];
            n += 16;
            b1 = *(const bf16x8*)&Bs[n * 128 + ((g ^ (n & 7)) * 8)];
        }
        #pragma unroll
        for (int mi = 0; mi < 4; ++mi) {
            int r = wm * 64 + mi * 16 + lr;
            bf16x8 a = *(const bf16x8*)&As[r * 128 + ((g ^ (r & 7)) * 8)];
            acc[mi][0] = __builtin_amdgcn_mfma_f32_16x16x32_bf16(a, b0, acc[mi][0], 0, 0, 0);
            acc[mi][1] = __builtin_amdgcn_mfma_f32_16x16x32_bf16(a, b1, acc[mi][1], 0, 0, 0);
        }
    }
    #pragma unroll
    for (int mi = 0; mi < 4; ++mi)
        #pragma unroll
        for (int ni = 0; ni < 2; ++ni)
            #pragma unroll
            for (int j = 0; j < 4; ++j) {
                int gr = row0 + wm * 64 + mi * 16 + lg * 4 + j;
                if (gr >= NN) continue;
                int n = wn * 32 + ni * 16 + lr;
                float val = acc[mi][ni][j];
                if (n < 32) xl2[(size_t)gr * 32 + n] = (fp16_t)val;
                else xr2[(size_t)gr * 32 + (n - 32)] = val;
            }
}

// ---------------------------------------------------------------- GAT2: packed-fp16, 8 lanes x 4ch per edge, 8 subgroups, depth-3
__global__ __launch_bounds__(256) void k_gat2(const int* __restrict__ perm,
                                              const fp16_t* __restrict__ xl2,
                                              const float* __restrict__ xr2,
                                              const float* __restrict__ mattr,
                                              const int* __restrict__ offs,
                                              const int* __restrict__ deg,
                                              const int2* __restrict__ ep8,
                                              const float* __restrict__ att2,
                                              const float* __restrict__ we2_,
                                              const float* __restrict__ b2,
                                              float* __restrict__ h3,
                                              float* __restrict__ acsr,
                                              float* __restrict__ Inv,
                                              float* __restrict__ wout) {
    int gid = (blockIdx.x * 256 + threadIdx.x) >> 6;
    if (gid >= NN) return;
    int v = perm[gid];
    int lane = threadIdx.x & 63;
    int sub = lane >> 3;
    int l = lane & 7;
    int c0 = l * 4;
    fp16x2 at2[2], we2[2], xr2v[2];
    {
        float4 atv = *(const float4*)(att2 + c0);
        float4 wev = *(const float4*)(we2_ + c0);
        float4 xrv = *(const float4*)(xr2 + (size_t)v * 32 + c0);
        at2[0] = fp16x2{(fp16_t)(atv.x * LOG2E), (fp16_t)(atv.y * LOG2E)};
        at2[1] = fp16x2{(fp16_t)(atv.z * LOG2E), (fp16_t)(atv.w * LOG2E)};
        we2[0] = fp16x2{(fp16_t)wev.x, (fp16_t)wev.y};
        we2[1] = fp16x2{(fp16_t)wev.z, (fp16_t)wev.w};
        xr2v[0] = fp16x2{(fp16_t)xrv.x, (fp16_t)xrv.y};
        xr2v[1] = fp16x2{(fp16_t)xrv.z, (fp16_t)xrv.w};
    }
    float den = 0.f;
    fp16x2 n2[2] = {};
    int st = offs[v], dg = deg[v];
    int i = sub;
    int2 e0 = make_int2(0, 0), e1 = make_int2(0, 0), e2 = make_int2(0, 0);
    fp16x4 a0 = {}, a1 = {};
    if (i < dg) e0 = ep8[st + i];
    if (i + 8 < dg) e1 = ep8[st + i + 8];
    if (i + 16 < dg) e2 = ep8[st + i + 16];
    if (i < dg) a0 = *(const fp16x4*)(xl2 + (size_t)e0.x * 32 + c0);
    if (i + 8 < dg) a1 = *(const fp16x4*)(xl2 + (size_t)e1.x * 32 + c0);

#define GAT2_BODY                                                    \
    {                                                                \
        float ea_ = __int_as_float(e0.y);                            \
        fp16x2 ea2 = bc2(ea_);                                       \
        const fp16x2* xp = (const fp16x2*)&a0;                       \
        fp16x2 q2 = {};                                              \
        _Pragma("unroll")                                            \
        for (int j = 0; j < 2; ++j) {                                \
            fp16x2 w = xp[j] + (ea2 * we2[j] + xr2v[j]);             \
            w = leaky2(w);                                           \
            q2 = q2 + w * at2[j];                                    \
        }                                                            \
        float q = (float)q2[0] + (float)q2[1];                       \
        q += __shfl_xor(q, 1, 8);                                    \
        q += __shfl_xor(q, 2, 8);                                    \
        q += __shfl_xor(q, 4, 8);                                    \
        if (l == 0) acsr[st + i] = q;                                \
        float ex = exp2f(q - QBIAS);                                 \
        den += ex;                                                   \
        fp16x2 ex2 = bc2(ex);                                        \
        _Pragma("unroll")                                            \
        for (int j = 0; j < 2; ++j) n2[j] = n2[j] + ex2 * xp[j];     \
        e0 = e1; e1 = e2; e2 = e3; a0 = a1; a1 = a2;                 \
    }

    #pragma unroll 2
    for (; i + 24 < dg; i += 8) {
        fp16x4 a2 = *(const fp16x4*)(xl2 + (size_t)e2.x * 32 + c0);
        int2 e3 = ep8[st + i + 24];
        GAT2_BODY
    }
    for (; i < dg; i += 8) {
        fp16x4 a2 = {};
        int2 e3 = make_int2(0, 0);
        if (i + 16 < dg) a2 = *(const fp16x4*)(xl2 + (size_t)e2.x * 32 + c0);
        GAT2_BODY
    }
#undef GAT2_BODY

    // merge 8 subgroup states (plain sums)
    #pragma unroll
    for (int w_ = 8; w_ <= 32; w_ <<= 1) {
        den += __shfl_xor(den, w_, 64);
        #pragma unroll
        for (int j = 0; j < 2; ++j) n2[j] = n2[j] + shfl_p2(n2[j], w_);
    }
    float n[4] = {(float)n2[0][0], (float)n2[0][1], (float)n2[1][0], (float)n2[1][1]};
    // self loop
    float eav = mattr[v];
    fp16x4 sv = *(const fp16x4*)(xl2 + (size_t)v * 32 + c0);
    const fp16x2* xsp = (const fp16x2*)&sv;
    float qs;
    {
        fp16x2 ea2 = bc2(eav);
        fp16x2 q2 = {};
        #pragma unroll
        for (int j = 0; j < 2; ++j) {
            fp16x2 w = xsp[j] + (ea2 * we2[j] + xr2v[j]);
            w = leaky2(w);
            q2 = q2 + w * at2[j];
        }
        qs = (float)q2[0] + (float)q2[1];
        qs += __shfl_xor(qs, 1, 8);
        qs += __shfl_xor(qs, 2, 8);
        qs += __shfl_xor(qs, 4, 8);
        float ex = exp2f(qs - QBIAS);
        den += ex;
        n[0] = fmaf(ex, (float)xsp[0][0], n[0]);
        n[1] = fmaf(ex, (float)xsp[0][1], n[1]);
        n[2] = fmaf(ex, (float)xsp[1][0], n[2]);
        n[3] = fmaf(ex, (float)xsp[1][1], n[3]);
    }
    float inv = 1.0f / (den + 1e-16f);
    if (lane == 0) {
        Inv[v] = inv;
        wout[EE + v] = exp2f(qs - QBIAS) * inv;
    }
    if (sub == 0) {
        float4 bb = *(const float4*)(b2 + c0);
        float b_[4] = {bb.x, bb.y, bb.z, bb.w};
        float4 r;
        float* rp = &r.x;
        #pragma unroll
        for (int j = 0; j < 4; ++j) {
            float o = n[j] * inv + b_[j];
            rp[j] = (o > 0.f) ? o : (__expf(o) - 1.0f);
        }
        *(float4*)(h3 + (size_t)v * 32 + c0) = r;
    }
}

// ---------------------------------------------------------------- finalize attention weights (original edge order)
__global__ __launch_bounds__(256) void k_wfinal(const int* __restrict__ ei,
                                                const int* __restrict__ offs,
                                                const int* __restrict__ slot,
                                                const float* __restrict__ acsr,
                                                const float* __restrict__ Inv,
                                                float* __restrict__ wout) {
    int e = blockIdx.x * 256 + threadIdx.x;
    if (e >= EE) return;
    int d = ei[EE + e];
    float al = acsr[offs[d] + slot[e]];
    wout[e] = exp2f(al - QBIAS) * Inv[d];
}

// ---------------------------------------------------------------- heads
__global__ __launch_bounds__(256) void k_head(const float* __restrict__ h3,
                                              const float* __restrict__ fc1W,
                                              const float* __restrict__ fc1b,
                                              const float* __restrict__ Wc,
                                              const float* __restrict__ bc,
                                              const float* __restrict__ Wt,
                                              const float* __restrict__ bt,
                                              float* __restrict__ outp) {
    __shared__ float sW1[32 * 32];
    __shared__ float sWc[32 * NCLONE];
    __shared__ float sWt[32 * NTYPE];
    __shared__ float sb1[32], sbc[NCLONE], sbt[NTYPE];
    int tid = threadIdx.x;
    for (int i = tid; i < 1024; i += 256) sW1[i] = fc1W[i];
    for (int i = tid; i < 32 * NCLONE; i += 256) sWc[i] = Wc[i];
    for (int i = tid; i < 32 * NTYPE; i += 256) sWt[i] = Wt[i];
    if (tid < 32) sb1[tid] = fc1b[tid];
    if (tid < NCLONE) sbc[tid] = bc[tid];
    if (tid < NTYPE) sbt[tid] = bt[tid];
    __syncthreads();
    int g = tid >> 5, l = tid & 31;
    int v = blockIdx.x * 8 + g;
    if (v >= NN) return;
    float x = h3[(size_t)v * CCH + l];
    float acc = sb1[l];
    #pragma unroll
    for (int c = 0; c < 32; ++c) {
        float xc = __shfl(x, c, 32);
        acc += xc * sW1[c * 32 + l];
    }
    float hl = fmaxf(acc, 0.0f);
    float at = (l < NTYPE) ? sbt[l] : 0.0f;
    float ac = (l < NCLONE) ? sbc[l] : 0.0f;
    #pragma unroll
    for (int c = 0; c < 32; ++c) {
        float hc = __shfl(hl, c, 32);
        float wt_ = (l < NTYPE) ? sWt[c * NTYPE + l] : 0.0f;
        float wc_ = (l < NCLONE) ? sWc[c * NCLONE + l] : 0.0f;
        at += hc * wt_;
        ac += hc * wc_;
    }
    float vt = (l < NTYPE) ? at : -INFINITY;
    float mt = vt;
    mt = fmaxf(mt, __shfl_xor(mt, 16, 32));
    mt = fmaxf(mt, __shfl_xor(mt, 8, 32));
    mt = fmaxf(mt, __shfl_xor(mt, 4, 32));
    mt = fmaxf(mt, __shfl_xor(mt, 2, 32));
    mt = fmaxf(mt, __shfl_xor(mt, 1, 32));
    float et = __expf(vt - mt);
    float stt = et;
    stt += __shfl_xor(stt, 16, 32);
    stt += __shfl_xor(stt, 8, 32);
    stt += __shfl_xor(stt, 4, 32);
    stt += __shfl_xor(stt, 2, 32);
    stt += __shfl_xor(stt, 1, 32);
    float lt = vt - mt - logf(stt);
    float vc = (l < NCLONE) ? ac : -INFINITY;
    float mc = vc;
    mc = fmaxf(mc, __shfl_xor(mc, 16, 32));
    mc = fmaxf(mc, __shfl_xor(mc, 8, 32));
    mc = fmaxf(mc, __shfl_xor(mc, 4, 32));
    mc = fmaxf(mc, __shfl_xor(mc, 2, 32));
    mc = fmaxf(mc, __shfl_xor(mc, 1, 32));
    float ec = __expf(vc - mc);
    float sc = ec;
    sc += __shfl_xor(sc, 16, 32);
    sc += __shfl_xor(sc, 8, 32);
    sc += __shfl_xor(sc, 4, 32);
    sc += __shfl_xor(sc, 2, 32);
    sc += __shfl_xor(sc, 1, 32);
    float lc = vc - mc - logf(sc);
    size_t ob = (size_t)v * 48;
    if (l < NCLONE) outp[ob + l] = lc;
    if (l < NTYPE) outp[ob + NCLONE + l] = lt;
}

// ---------------------------------------------------------------- launcher
extern "C" void kernel_launch(void* const* d_in, const int* in_sizes, int n_in,
                              void* d_out, int out_size, void* d_ws, size_t ws_size,
                              hipStream_t stream) {
    const float* x     = (const float*)d_in[0];
    const int*   ei    = (const int*)d_in[1];
    const float* ea    = (const float*)d_in[2];
    const float* Wl1   = (const float*)d_in[3];
    const float* Wr1   = (const float*)d_in[4];
    const float* We1   = (const float*)d_in[5];
    const float* att1  = (const float*)d_in[6];
    const float* b1    = (const float*)d_in[7];
    const float* skipW = (const float*)d_in[8];
    const float* skipb = (const float*)d_in[9];
    const float* bng   = (const float*)d_in[10];
    const float* bnb   = (const float*)d_in[11];
    const float* Wl2   = (const float*)d_in[12];
    const float* Wr2   = (const float*)d_in[13];
    const float* We2   = (const float*)d_in[14];
    const float* att2  = (const float*)d_in[15];
    const float* b2    = (const float*)d_in[16];
    const float* fc1W  = (const float*)d_in[17];
    const float* fc1b  = (const float*)d_in[18];
    const float* Wc    = (const float*)d_in[19];
    const float* bc    = (const float*)d_in[20];
    const float* Wt    = (const float*)d_in[21];
    const float* bt    = (const float*)d_in[22];
    float* out = (float*)d_out;
    float* wout = out + (size_t)NN * 48;

    const size_t NF = (size_t)NN * FIN;   // 12.8M elems
    char* w = (char*)d_ws;
    fp16_t* xl1h = (fp16_t*)w;  w += NF * 2;
    fp16_t* xr1h = (fp16_t*)w;  w += NF * 2;
    fp16_t* skb  = (fp16_t*)w;  w += NF * 2;
    bf16_t* hb   = (bf16_t*)w;  w += NF * 2;
    int2*   ep8  = (int2*)w;    w += (size_t)EE * 8;
    float*  acsr = (float*)w;   w += (size_t)EE * 4;
    int*    slot = (int*)w;     w += (size_t)EE * 4;
    int* deg   = (int*)w;   w += (size_t)NN * 4;
    int* offs  = (int*)w;   w += (size_t)NN * 4;
    float* mattr = (float*)w; w += (size_t)NN * 4;
    float* Inv   = (float*)w; w += (size_t)NN * 4;
    int*   perm  = (int*)w;   w += (size_t)NN * 4;
    int*   bsum  = (int*)w;   w += 64 * 4;
    float* bns   = (float*)w; w += 128 * 4;
    float* bnq   = (float*)w; w += 128 * 4;
    int*   hist  = (int*)w;   w += NBIN * 4;
    int*   binpos= (int*)w;   w += NBIN * 4;
    float* scl   = (float*)w; w += 128 * 4;
    float* shf   = (float*)w; w += 128 * 4;
    bf16_t* WbT  = (bf16_t*)w; w += 384 * 128 * 2;
    bf16_t* Wb2T = (bf16_t*)w; w += 64 * 128 * 2;
    // aliases into dead regions (after gat1):
    fp16_t* xl2h = xl1h;              // 6.4 MB
    float*  xr2  = (float*)xr1h;      // 12.8 MB
    float*  h3   = (float*)skb;       // 12.8 MB

    hipMemsetAsync(deg, 0, (size_t)NN * sizeof(int), stream);
    hipMemsetAsync(bns, 0, (256 + NBIN) * sizeof(float), stream);   // bns + bnq + hist

    k_wcvt<<<224, 256, 0, stream>>>(Wl1, Wr1, skipW, Wl2, Wr2, WbT, Wb2T);

    k_deg<<<6250, 256, 0, stream>>>(ei, deg, slot);
    k_scan1<<<SCAN_B, 256, 0, stream>>>(deg, offs, bsum, hist);
    k_serial<<<1, 64, 0, stream>>>(bsum, hist, binpos);
    k_scan3<<<391, 256, 0, stream>>>(offs, bsum);
    k_scat<<<391, 256, 0, stream>>>(deg, binpos, perm);
    k_fill<<<6250, 256, 0, stream>>>(ei, ea, offs, slot, ep8);

    k_gemm1<<<782, 256, 0, stream>>>(x, WbT, xl1h, xr1h, skb);
    k_gat1<<<25000, 256, 0, stream>>>(perm, xl1h, xr1h, skb, offs, deg, ep8,
                                      att1, We1, b1, skipb, hb, mattr);
    k_bnstats<<<128, 256, 0, stream>>>(hb, bns, bnq);
    k_bnfinal<<<1, 128, 0, stream>>>(bns, bnq, bng, bnb, scl, shf);
    k_gemm2<<<782, 256, 0, stream>>>(hb, scl, shf, Wb2T, xl2h, xr2);
    k_gat2<<<25000, 256, 0, stream>>>(perm, xl2h, xr2, mattr, offs, deg, ep8,
                                      att2, We2, b2, h3, acsr, Inv, wout);
    k_wfinal<<<6250, 256, 0, stream>>>(ei, offs, slot, acsr, Inv, wout);
    k_head<<<12500, 256, 0, stream>>>(h3, fc1W, fc1b, Wc, bc, Wt, bt, out);
}

// Round 13
// 420.317 us; speedup vs baseline: 1.1759x; 1.0118x over previous
//
#include <hip/hip_runtime.h>
#include <math.h>

// Problem constants
#define NN 100000
#define EE 1600000
#define FIN 128
#define HCH 128     // H*C for gat1
#define CCH 32      // C
#define NCLONE 19
#define NTYPE 29
#define ETOT (EE + NN)
#define SCAN_B 49   // ceil(NN / 2048)
#define NBIN 128
#define LOG2E 1.4426950408889634f
#define QBIAS 5.0f

typedef __bf16 bf16_t;
typedef bf16_t bf16x8 __attribute__((ext_vector_type(8)));
typedef _Float16 fp16_t;
typedef fp16_t fp16x2 __attribute__((ext_vector_type(2)));
typedef fp16_t fp16x4 __attribute__((ext_vector_type(4)));
typedef fp16_t fp16x8 __attribute__((ext_vector_type(8)));
typedef float f32x4 __attribute__((ext_vector_type(4)));

static __device__ __forceinline__ fp16x2 shfl_p2(fp16x2 v, int mask) {
    float f = __shfl_xor(__builtin_bit_cast(float, v), mask, 64);
    return __builtin_bit_cast(fp16x2, f);
}
static __device__ __forceinline__ fp16x2 bc2(float f) {
    fp16_t h = (fp16_t)f;
    fp16x2 r = {h, h};
    return r;
}
// leaky_relu(w, 0.2) == max(w, 0.2*w)  -> v_pk_mul_f16 + v_pk_max_f16
static __device__ __forceinline__ fp16x2 leaky2(fp16x2 w) {
    const fp16x2 c02 = {(fp16_t)0.2f, (fp16_t)0.2f};
    return __builtin_elementwise_max(w, w * c02);
}

// ---------------------------------------------------------------- weight conversion
__global__ __launch_bounds__(256) void k_wcvt(const float* __restrict__ Wl1,
                                              const float* __restrict__ Wr1,
                                              const float* __restrict__ Ws,
                                              const float* __restrict__ Wl2,
                                              const float* __restrict__ Wr2,
                                              bf16_t* __restrict__ WbT,
                                              bf16_t* __restrict__ Wb2T) {
    int t = blockIdx.x * 256 + threadIdx.x;
    if (t < 384 * 128) {
        int n = t >> 7, k = t & 127;
        const float* W = (n < 128) ? Wl1 : ((n < 256) ? Wr1 : Ws);
        WbT[t] = (bf16_t)W[k * 128 + (n & 127)];
    } else if (t < 384 * 128 + 64 * 128) {
        int u = t - 384 * 128;
        int n = u >> 7, k = u & 127;
        const float* W = (n < 32) ? Wl2 : Wr2;
        Wb2T[u] = (bf16_t)W[k * 32 + (n & 31)];
    }
}

// ---------------------------------------------------------------- degree + slot
__global__ __launch_bounds__(256) void k_deg(const int* __restrict__ ei,
                                             int* __restrict__ deg,
                                             int* __restrict__ slot) {
    int e = blockIdx.x * 256 + threadIdx.x;
    if (e < EE) {
        int d = ei[EE + e];
        slot[e] = atomicAdd(&deg[d], 1);
    }
}

// ---------------------------------------------------------------- exclusive scan of deg + degree histogram (fused)
__global__ __launch_bounds__(256) void k_scan1(const int* __restrict__ deg,
                                               int* __restrict__ offs,
                                               int* __restrict__ bsum,
                                               int* __restrict__ hist) {
    __shared__ int tsum[256];
    __shared__ int lh[NBIN];
    int b = blockIdx.x, tid = threadIdx.x;
    if (tid < NBIN) lh[tid] = 0;
    int base = b * 2048;
    int loc[8], dv[8];
    int s = 0;
    #pragma unroll
    for (int i = 0; i < 8; ++i) {
        int idx = base + tid * 8 + i;
        int d = (idx < NN) ? deg[idx] : 0;
        dv[i] = (idx < NN) ? d : -1;
        loc[i] = s; s += d;
    }
    tsum[tid] = s;
    __syncthreads();
    #pragma unroll
    for (int i = 0; i < 8; ++i)
        if (dv[i] >= 0) atomicAdd(&lh[min(dv[i], NBIN - 1)], 1);
    for (int off = 1; off < 256; off <<= 1) {
        int v = (tid >= off) ? tsum[tid - off] : 0;
        __syncthreads();
        tsum[tid] += v;
        __syncthreads();
    }
    int texcl = tsum[tid] - s;
    #pragma unroll
    for (int i = 0; i < 8; ++i) {
        int idx = base + tid * 8 + i;
        if (idx < NN) offs[idx] = texcl + loc[i];
    }
    if (tid == 255) bsum[b] = tsum[255];
    __syncthreads();
    if (tid < NBIN && lh[tid]) atomicAdd(&hist[tid], lh[tid]);
}

// serial: bsum prefix + descending-degree binpos
__global__ void k_serial(int* __restrict__ bsum,
                         const int* __restrict__ hist,
                         int* __restrict__ binpos) {
    if (threadIdx.x == 0) {
        int run = 0;
        for (int i = 0; i < SCAN_B; ++i) { int t = bsum[i]; bsum[i] = run; run += t; }
        run = 0;
        for (int b = NBIN - 1; b >= 0; --b) { binpos[b] = run; run += hist[b]; }
    }
}

// scatter perm + offs fixup (fused former k_scan3)
__global__ __launch_bounds__(256) void k_scat(const int* __restrict__ deg,
                                              int* __restrict__ binpos,
                                              int* __restrict__ perm,
                                              int* __restrict__ offs,
                                              const int* __restrict__ bsum) {
    __shared__ int lcnt[NBIN];
    __shared__ int lbase[NBIN];
    int tid = threadIdx.x;
    if (tid < NBIN) lcnt[tid] = 0;
    __syncthreads();
    int v = blockIdx.x * 256 + tid;
    int b = 0, r = 0;
    bool ok = (v < NN);
    if (ok) {
        offs[v] += bsum[v >> 11];
        b = min(deg[v], NBIN - 1);
        r = atomicAdd(&lcnt[b], 1);
    }
    __syncthreads();
    if (tid < NBIN && lcnt[tid]) lbase[tid] = atomicAdd(&binpos[tid], lcnt[tid]);
    __syncthreads();
    if (ok) perm[lbase[b] + r] = v;
}

// ---------------------------------------------------------------- CSR fill (atomic-free)
__global__ __launch_bounds__(256) void k_fill(const int* __restrict__ ei,
                                              const float* __restrict__ ea,
                                              const int* __restrict__ offs,
                                              const int* __restrict__ slot,
                                              int2* __restrict__ ep8) {
    int e = blockIdx.x * 256 + threadIdx.x;
    if (e < EE) {
        int d = ei[EE + e];
        int pos = offs[d] + slot[e];
        ep8[pos] = make_int2(ei[e], __float_as_int(ea[e]));
    }
}

// ---------------------------------------------------------------- GEMM1 (MFMA): x(f32) @ WbT^T -> [xl1|xr1|skb] (fp16)
__global__ __launch_bounds__(256) void k_gemm1(const float* __restrict__ x,
                                               const bf16_t* __restrict__ WbT,
                                               fp16_t* __restrict__ xl,
                                               fp16_t* __restrict__ xr,
                                               fp16_t* __restrict__ sk) {
    __shared__ bf16_t As[128 * 128];
    __shared__ bf16_t Bs[128 * 128];
    const int tid = threadIdx.x;
    const int row0 = blockIdx.x * 128;
    #pragma unroll
    for (int i = 0; i < 8; ++i) {
        int c = i * 256 + tid;
        int r = c >> 4, g = c & 15;
        int gr = row0 + r;
        bf16x8 v = {};
        if (gr < NN) {
            float4 f0 = *(const float4*)(x + (size_t)gr * 128 + g * 8);
            float4 f1 = *(const float4*)(x + (size_t)gr * 128 + g * 8 + 4);
            v[0] = (bf16_t)f0.x; v[1] = (bf16_t)f0.y; v[2] = (bf16_t)f0.z; v[3] = (bf16_t)f0.w;
            v[4] = (bf16_t)f1.x; v[5] = (bf16_t)f1.y; v[6] = (bf16_t)f1.z; v[7] = (bf16_t)f1.w;
        }
        *(bf16x8*)&As[r * 128 + ((g ^ (r & 7)) * 8)] = v;
    }

    const int wid = tid >> 6, lane = tid & 63;
    const int wm = wid >> 1, wn = wid & 1;
    const int lr = lane & 15, lg = lane >> 4;

    for (int chunk = 0; chunk < 3; ++chunk) {
        const int col0 = chunk * 128;
        fp16_t* __restrict__ out = (chunk == 0) ? xl : ((chunk == 1) ? xr : sk);
        __syncthreads();
        #pragma unroll
        for (int i = 0; i < 8; ++i) {
            int c = i * 256 + tid;
            int n = c >> 4, g = c & 15;
            bf16x8 v = *(const bf16x8*)(WbT + (size_t)(col0 + n) * 128 + g * 8);
            *(bf16x8*)&Bs[n * 128 + ((g ^ (n & 7)) * 8)] = v;
        }
        __syncthreads();

        f32x4 acc[4][4] = {};
        #pragma unroll
        for (int ks = 0; ks < 4; ++ks) {
            int g = ks * 4 + lg;
            bf16x8 b[4];
            #pragma unroll
            for (int ni = 0; ni < 4; ++ni) {
                int n = wn * 64 + ni * 16 + lr;
                b[ni] = *(const bf16x8*)&Bs[n * 128 + ((g ^ (n & 7)) * 8)];
            }
            #pragma unroll
            for (int mi = 0; mi < 4; ++mi) {
                int r = wm * 64 + mi * 16 + lr;
                bf16x8 a = *(const bf16x8*)&As[r * 128 + ((g ^ (r & 7)) * 8)];
                #pragma unroll
                for (int ni = 0; ni < 4; ++ni)
                    acc[mi][ni] = __builtin_amdgcn_mfma_f32_16x16x32_bf16(a, b[ni], acc[mi][ni], 0, 0, 0);
            }
        }
        #pragma unroll
        for (int mi = 0; mi < 4; ++mi)
            #pragma unroll
            for (int ni = 0; ni < 4; ++ni)
                #pragma unroll
                for (int j = 0; j < 4; ++j) {
                    int gr = row0 + wm * 64 + mi * 16 + lg * 4 + j;
                    if (gr >= NN) continue;
                    int n = wn * 64 + ni * 16 + lr;
                    out[(size_t)gr * 128 + n] = (fp16_t)acc[mi][ni][j];
                }
    }
}

// ---------------------------------------------------------------- GAT1: packed-fp16, 16 lanes x 8ch per edge, 4 subgroups, depth-3
__global__ __launch_bounds__(256) void k_gat1(const int* __restrict__ perm,
                                              const fp16_t* __restrict__ xl1,
                                              const fp16_t* __restrict__ xr1,
                                              const fp16_t* __restrict__ skb,
                                              const int* __restrict__ offs,
                                              const int* __restrict__ deg,
                                              const int2* __restrict__ ep8,
                                              const float* __restrict__ att1,
                                              const float* __restrict__ we1,
                                              const float* __restrict__ b1,
                                              const float* __restrict__ skipb,
                                              bf16_t* __restrict__ hb,
                                              float* __restrict__ mattr) {
    int gid = (blockIdx.x * 256 + threadIdx.x) >> 6;
    if (gid >= NN) return;
    int v = perm[gid];
    int lane = threadIdx.x & 63;
    int sub = lane >> 4;
    int l = lane & 15;
    int c0 = l * 8;
    fp16x2 at2[4], we2[4], xr2v[4];
    {
        float4 t0 = *(const float4*)(att1 + c0);
        float4 t1 = *(const float4*)(att1 + c0 + 4);
        at2[0] = fp16x2{(fp16_t)(t0.x * LOG2E), (fp16_t)(t0.y * LOG2E)};
        at2[1] = fp16x2{(fp16_t)(t0.z * LOG2E), (fp16_t)(t0.w * LOG2E)};
        at2[2] = fp16x2{(fp16_t)(t1.x * LOG2E), (fp16_t)(t1.y * LOG2E)};
        at2[3] = fp16x2{(fp16_t)(t1.z * LOG2E), (fp16_t)(t1.w * LOG2E)};
        float4 w0 = *(const float4*)(we1 + c0);
        float4 w1 = *(const float4*)(we1 + c0 + 4);
        we2[0] = fp16x2{(fp16_t)w0.x, (fp16_t)w0.y};
        we2[1] = fp16x2{(fp16_t)w0.z, (fp16_t)w0.w};
        we2[2] = fp16x2{(fp16_t)w1.x, (fp16_t)w1.y};
        we2[3] = fp16x2{(fp16_t)w1.z, (fp16_t)w1.w};
        fp16x8 xrv = *(const fp16x8*)(xr1 + (size_t)v * 128 + c0);
        const fp16x2* xp = (const fp16x2*)&xrv;
        xr2v[0] = xp[0]; xr2v[1] = xp[1]; xr2v[2] = xp[2]; xr2v[3] = xp[3];
    }
    float den = 0.f, easum = 0.f;
    fp16x2 n2[4] = {};
    int st = offs[v], dg = deg[v];
    int i = sub;
    int2 e0 = make_int2(0, 0), e1 = make_int2(0, 0), e2 = make_int2(0, 0);
    fp16x8 a0 = {}, a1 = {};
    if (i < dg) e0 = ep8[st + i];
    if (i + 4 < dg) e1 = ep8[st + i + 4];
    if (i + 8 < dg) e2 = ep8[st + i + 8];
    if (i < dg) a0 = *(const fp16x8*)(xl1 + (size_t)e0.x * 128 + c0);
    if (i + 4 < dg) a1 = *(const fp16x8*)(xl1 + (size_t)e1.x * 128 + c0);

#define GAT1_BODY                                                    \
    {                                                                \
        float ea_ = __int_as_float(e0.y);                            \
        easum += ea_;                                                \
        fp16x2 ea2 = bc2(ea_);                                       \
        const fp16x2* xp = (const fp16x2*)&a0;                       \
        fp16x2 q2 = {};                                              \
        _Pragma("unroll")                                            \
        for (int j = 0; j < 4; ++j) {                                \
            fp16x2 w = xp[j] + (ea2 * we2[j] + xr2v[j]);             \
            w = leaky2(w);                                           \
            q2 = q2 + w * at2[j];                                    \
        }                                                            \
        float q = (float)q2[0] + (float)q2[1];                       \
        q += __shfl_xor(q, 1, 4);                                    \
        q += __shfl_xor(q, 2, 4);                                    \
        float ex = exp2f(q - QBIAS);                                 \
        den += ex;                                                   \
        fp16x2 ex2 = bc2(ex);                                        \
        _Pragma("unroll")                                            \
        for (int j = 0; j < 4; ++j) n2[j] = n2[j] + ex2 * xp[j];     \
        e0 = e1; e1 = e2; e2 = e3; a0 = a1; a1 = a2;                 \
    }

    #pragma unroll 2
    for (; i + 12 < dg; i += 4) {
        fp16x8 a2 = *(const fp16x8*)(xl1 + (size_t)e2.x * 128 + c0);
        int2 e3 = ep8[st + i + 12];
        GAT1_BODY
    }
    for (; i < dg; i += 4) {
        fp16x8 a2 = {};
        int2 e3 = make_int2(0, 0);
        if (i + 8 < dg) a2 = *(const fp16x8*)(xl1 + (size_t)e2.x * 128 + c0);
        GAT1_BODY
    }
#undef GAT1_BODY

    // merge 4 subgroup states (plain sums)
    #pragma unroll
    for (int w_ = 16; w_ <= 32; w_ <<= 1) {
        den += __shfl_xor(den, w_, 64);
        easum += __shfl_xor(easum, w_, 64);
        #pragma unroll
        for (int j = 0; j < 4; ++j) n2[j] = n2[j] + shfl_p2(n2[j], w_);
    }
    // unpack n to f32
    float n[8];
    #pragma unroll
    for (int j = 0; j < 4; ++j) { n[2 * j] = (float)n2[j][0]; n[2 * j + 1] = (float)n2[j][1]; }
    // self loop (mean edge attr)
    float eav = easum / fmaxf((float)dg, 1.0f);
    if (lane == 0) mattr[v] = eav;
    fp16x8 svv = *(const fp16x8*)(xl1 + (size_t)v * 128 + c0);
    const fp16x2* xsp = (const fp16x2*)&svv;
    {
        fp16x2 ea2 = bc2(eav);
        fp16x2 q2 = {};
        #pragma unroll
        for (int j = 0; j < 4; ++j) {
            fp16x2 w = xsp[j] + (ea2 * we2[j] + xr2v[j]);
            w = leaky2(w);
            q2 = q2 + w * at2[j];
        }
        float qs = (float)q2[0] + (float)q2[1];
        qs += __shfl_xor(qs, 1, 4);
        qs += __shfl_xor(qs, 2, 4);
        float ex = exp2f(qs - QBIAS);
        den += ex;
        #pragma unroll
        for (int j = 0; j < 4; ++j) {
            n[2 * j]     = fmaf(ex, (float)xsp[j][0], n[2 * j]);
            n[2 * j + 1] = fmaf(ex, (float)xsp[j][1], n[2 * j + 1]);
        }
    }
    if (sub == 0) {
        float inv = 1.0f / (den + 1e-16f);
        float4 bb0 = *(const float4*)(b1 + c0);
        float4 bb1 = *(const float4*)(b1 + c0 + 4);
        float4 sb0 = *(const float4*)(skipb + c0);
        float4 sb1 = *(const float4*)(skipb + c0 + 4);
        fp16x8 skv = *(const fp16x8*)(skb + (size_t)v * 128 + c0);
        float bb[8] = {bb0.x, bb0.y, bb0.z, bb0.w, bb1.x, bb1.y, bb1.z, bb1.w};
        float sv[8] = {sb0.x, sb0.y, sb0.z, sb0.w, sb1.x, sb1.y, sb1.z, sb1.w};
        bf16x8 r;
        #pragma unroll
        for (int j = 0; j < 8; ++j)
            r[j] = (bf16_t)(n[j] * inv + bb[j] + (float)skv[j] + sv[j]);
        *(bf16x8*)(hb + (size_t)v * 128 + c0) = r;
    }
}

// ---------------------------------------------------------------- batchnorm stats
__global__ __launch_bounds__(256) void k_bnstats(const bf16_t* __restrict__ h,
                                                 float* __restrict__ bns,
                                                 float* __restrict__ bnq) {
    __shared__ float sS[16 * 128];
    __shared__ float sQ[16 * 128];
    int tid = threadIdx.x;
    int cg = tid & 15;
    int slot = tid >> 4;
    int c0 = cg * 8;
    float s[8] = {}, q[8] = {};
    for (int r = blockIdx.x * 16 + slot; r < NN; r += gridDim.x * 16) {
        bf16x8 v = *(const bf16x8*)&h[(size_t)r * 128 + c0];
        #pragma unroll
        for (int j = 0; j < 8; ++j) { float f = (float)v[j]; s[j] += f; q[j] += f * f; }
    }
    #pragma unroll
    for (int j = 0; j < 8; ++j) { sS[slot * 128 + c0 + j] = s[j]; sQ[slot * 128 + c0 + j] = q[j]; }
    __syncthreads();
    if (tid < 128) {
        float as = 0.f, aq = 0.f;
        #pragma unroll
        for (int k = 0; k < 16; ++k) { as += sS[k * 128 + tid]; aq += sQ[k * 128 + tid]; }
        atomicAdd(&bns[tid], as);
        atomicAdd(&bnq[tid], aq);
    }
}

__global__ void k_bnfinal(const float* __restrict__ bns, const float* __restrict__ bnq,
                          const float* __restrict__ g, const float* __restrict__ b,
                          float* __restrict__ scale, float* __restrict__ shift) {
    int c = threadIdx.x;
    if (c < 128) {
        float mu = bns[c] * (1.0f / NN);
        float var = bnq[c] * (1.0f / NN) - mu * mu;
        float rs = rsqrtf(var + 1e-5f);
        float a = rs * g[c];
        scale[c] = a;
        shift[c] = b[c] - mu * a;
    }
}

// ---------------------------------------------------------------- GEMM2 (MFMA): elu(bn(h_bf16)) @ Wb2T^T -> [xl2 fp16 | xr2 f32]
__global__ __launch_bounds__(256) void k_gemm2(const bf16_t* __restrict__ h,
                                               const float* __restrict__ scl,
                                               const float* __restrict__ shf,
                                               const bf16_t* __restrict__ Wb2T,
                                               fp16_t* __restrict__ xl2,
                                               float* __restrict__ xr2) {
    __shared__ bf16_t As[128 * 128];
    __shared__ bf16_t Bs[64 * 128];
    const int tid = threadIdx.x;
    const int row0 = blockIdx.x * 128;
    #pragma unroll
    for (int i = 0; i < 8; ++i) {
        int c = i * 256 + tid;
        int r = c >> 4, g = c & 15;
        int gr = row0 + r;
        bf16x8 v = {};
        if (gr < NN) {
            bf16x8 hv = *(const bf16x8*)(h + (size_t)gr * 128 + g * 8);
            float4 s0 = *(const float4*)(scl + g * 8);
            float4 s1 = *(const float4*)(scl + g * 8 + 4);
            float4 t0 = *(const float4*)(shf + g * 8);
            float4 t1 = *(const float4*)(shf + g * 8 + 4);
            float e[8];
            e[0] = (float)hv[0] * s0.x + t0.x; e[1] = (float)hv[1] * s0.y + t0.y;
            e[2] = (float)hv[2] * s0.z + t0.z; e[3] = (float)hv[3] * s0.w + t0.w;
            e[4] = (float)hv[4] * s1.x + t1.x; e[5] = (float)hv[5] * s1.y + t1.y;
            e[6] = (float)hv[6] * s1.z + t1.z; e[7] = (float)hv[7] * s1.w + t1.w;
            #pragma unroll
            for (int j = 0; j < 8; ++j) {
                float vv = e[j];
                vv = (vv > 0.f) ? vv : (__expf(vv) - 1.0f);
                v[j] = (bf16_t)vv;
            }
        }
        *(bf16x8*)&As[r * 128 + ((g ^ (r & 7)) * 8)] = v;
    }
    #pragma unroll
    for (int i = 0; i < 4; ++i) {
        int c = i * 256 + tid;
        int n = c >> 4, g = c & 15;
        bf16x8 v = *(const bf16x8*)(Wb2T + (size_t)n * 128 + g * 8);
        *(bf16x8*)&Bs[n * 128 + ((g ^ (n & 7)) * 8)] = v;
    }
    __syncthreads();

    const int wid = tid >> 6, lane = tid & 63;
    const int wm = wid >> 1, wn = wid & 1;
    const int lr = lane & 15, lg = lane >> 4;
    f32x4 acc[4][2] = {};
    #pragma unroll
    for (int ks = 0; ks < 4; ++ks) {
        int g = ks * 4 + lg;
        bf16x8 b0, b1;
        {
            int n = wn * 32 + lr;
            b0 = *(const bf16x8*)&Bs[n * 128 + ((g ^ (n & 7)) * 8)];
            n += 16;
            b1 = *(const bf16x8*)&Bs[n * 128 + ((g ^ (n & 7)) * 8)];
        }
        #pragma unroll
        for (int mi = 0; mi < 4; ++mi) {
            int r = wm * 64 + mi * 16 + lr;
            bf16x8 a = *(const bf16x8*)&As[r * 128 + ((g ^ (r & 7)) * 8)];
            acc[mi][0] = __builtin_amdgcn_mfma_f32_16x16x32_bf16(a, b0, acc[mi][0], 0, 0, 0);
            acc[mi][1] = __builtin_amdgcn_mfma_f32_16x16x32_bf16(a, b1, acc[mi][1], 0, 0, 0);
        }
    }
    #pragma unroll
    for (int mi = 0; mi < 4; ++mi)
        #pragma unroll
        for (int ni = 0; ni < 2; ++ni)
            #pragma unroll
            for (int j = 0; j < 4; ++j) {
                int gr = row0 + wm * 64 + mi * 16 + lg * 4 + j;
                if (gr >= NN) continue;
                int n = wn * 32 + ni * 16 + lr;
                float val = acc[mi][ni][j];
                if (n < 32) xl2[(size_t)gr * 32 + n] = (fp16_t)val;
                else xr2[(size_t)gr * 32 + (n - 32)] = val;
            }
}

// ---------------------------------------------------------------- GAT2: packed-fp16, 8 lanes x 4ch per edge, 8 subgroups, depth-3
__global__ __launch_bounds__(256) void k_gat2(const int* __restrict__ perm,
                                              const fp16_t* __restrict__ xl2,
                                              const float* __restrict__ xr2,
                                              const float* __restrict__ mattr,
                                              const int* __restrict__ offs,
                                              const int* __restrict__ deg,
                                              const int2* __restrict__ ep8,
                                              const float* __restrict__ att2,
                                              const float* __restrict__ we2_,
                                              const float* __restrict__ b2,
                                              float* __restrict__ h3,
                                              float* __restrict__ acsr,
                                              float* __restrict__ Inv,
                                              float* __restrict__ wout) {
    int gid = (blockIdx.x * 256 + threadIdx.x) >> 6;
    if (gid >= NN) return;
    int v = perm[gid];
    int lane = threadIdx.x & 63;
    int sub = lane >> 3;
    int l = lane & 7;
    int c0 = l * 4;
    fp16x2 at2[2], we2[2], xr2v[2];
    {
        float4 atv = *(const float4*)(att2 + c0);
        float4 wev = *(const float4*)(we2_ + c0);
        float4 xrv = *(const float4*)(xr2 + (size_t)v * 32 + c0);
        at2[0] = fp16x2{(fp16_t)(atv.x * LOG2E), (fp16_t)(atv.y * LOG2E)};
        at2[1] = fp16x2{(fp16_t)(atv.z * LOG2E), (fp16_t)(atv.w * LOG2E)};
        we2[0] = fp16x2{(fp16_t)wev.x, (fp16_t)wev.y};
        we2[1] = fp16x2{(fp16_t)wev.z, (fp16_t)wev.w};
        xr2v[0] = fp16x2{(fp16_t)xrv.x, (fp16_t)xrv.y};
        xr2v[1] = fp16x2{(fp16_t)xrv.z, (fp16_t)xrv.w};
    }
    float den = 0.f;
    fp16x2 n2[2] = {};
    int st = offs[v], dg = deg[v];
    int i = sub;
    int2 e0 = make_int2(0, 0), e1 = make_int2(0, 0), e2 = make_int2(0, 0);
    fp16x4 a0 = {}, a1 = {};
    if (i < dg) e0 = ep8[st + i];
    if (i + 8 < dg) e1 = ep8[st + i + 8];
    if (i + 16 < dg) e2 = ep8[st + i + 16];
    if (i < dg) a0 = *(const fp16x4*)(xl2 + (size_t)e0.x * 32 + c0);
    if (i + 8 < dg) a1 = *(const fp16x4*)(xl2 + (size_t)e1.x * 32 + c0);

#define GAT2_BODY                                                    \
    {                                                                \
        float ea_ = __int_as_float(e0.y);                            \
        fp16x2 ea2 = bc2(ea_);                                       \
        const fp16x2* xp = (const fp16x2*)&a0;                       \
        fp16x2 q2 = {};                                              \
        _Pragma("unroll")                                            \
        for (int j = 0; j < 2; ++j) {                                \
            fp16x2 w = xp[j] + (ea2 * we2[j] + xr2v[j]);             \
            w = leaky2(w);                                           \
            q2 = q2 + w * at2[j];                                    \
        }                                                            \
        float q = (float)q2[0] + (float)q2[1];                       \
        q += __shfl_xor(q, 1, 8);                                    \
        q += __shfl_xor(q, 2, 8);                                    \
        q += __shfl_xor(q, 4, 8);                                    \
        if (l == 0) acsr[st + i] = q;                                \
        float ex = exp2f(q - QBIAS);                                 \
        den += ex;                                                   \
        fp16x2 ex2 = bc2(ex);                                        \
        _Pragma("unroll")                                            \
        for (int j = 0; j < 2; ++j) n2[j] = n2[j] + ex2 * xp[j];     \
        e0 = e1; e1 = e2; e2 = e3; a0 = a1; a1 = a2;                 \
    }

    #pragma unroll 2
    for (; i + 24 < dg; i += 8) {
        fp16x4 a2 = *(const fp16x4*)(xl2 + (size_t)e2.x * 32 + c0);
        int2 e3 = ep8[st + i + 24];
        GAT2_BODY
    }
    for (; i < dg; i += 8) {
        fp16x4 a2 = {};
        int2 e3 = make_int2(0, 0);
        if (i + 16 < dg) a2 = *(const fp16x4*)(xl2 + (size_t)e2.x * 32 + c0);
        GAT2_BODY
    }
#undef GAT2_BODY

    // merge 8 subgroup states (plain sums)
    #pragma unroll
    for (int w_ = 8; w_ <= 32; w_ <<= 1) {
        den += __shfl_xor(den, w_, 64);
        #pragma unroll
        for (int j = 0; j < 2; ++j) n2[j] = n2[j] + shfl_p2(n2[j], w_);
    }
    float n[4] = {(float)n2[0][0], (float)n2[0][1], (float)n2[1][0], (float)n2[1][1]};
    // self loop
    float eav = mattr[v];
    fp16x4 sv = *(const fp16x4*)(xl2 + (size_t)v * 32 + c0);
    const fp16x2* xsp = (const fp16x2*)&sv;
    float qs;
    {
        fp16x2 ea2 = bc2(eav);
        fp16x2 q2 = {};
        #pragma unroll
        for (int j = 0; j < 2; ++j) {
            fp16x2 w = xsp[j] + (ea2 * we2[j] + xr2v[j]);
            w = leaky2(w);
            q2 = q2 + w * at2[j];
        }
        qs = (float)q2[0] + (float)q2[1];
        qs += __shfl_xor(qs, 1, 8);
        qs += __shfl_xor(qs, 2, 8);
        qs += __shfl_xor(qs, 4, 8);
        float ex = exp2f(qs - QBIAS);
        den += ex;
        n[0] = fmaf(ex, (float)xsp[0][0], n[0]);
        n[1] = fmaf(ex, (float)xsp[0][1], n[1]);
        n[2] = fmaf(ex, (float)xsp[1][0], n[2]);
        n[3] = fmaf(ex, (float)xsp[1][1], n[3]);
    }
    float inv = 1.0f / (den + 1e-16f);
    if (lane == 0) {
        Inv[v] = inv;
        wout[EE + v] = exp2f(qs - QBIAS) * inv;
    }
    if (sub == 0) {
        float4 bb = *(const float4*)(b2 + c0);
        float b_[4] = {bb.x, bb.y, bb.z, bb.w};
        float4 r;
        float* rp = &r.x;
        #pragma unroll
        for (int j = 0; j < 4; ++j) {
            float o = n[j] * inv + b_[j];
            rp[j] = (o > 0.f) ? o : (__expf(o) - 1.0f);
        }
        *(float4*)(h3 + (size_t)v * 32 + c0) = r;
    }
}

// ---------------------------------------------------------------- finalize attention weights (original edge order)
__global__ __launch_bounds__(256) void k_wfinal(const int* __restrict__ ei,
                                                const int* __restrict__ offs,
                                                const int* __restrict__ slot,
                                                const float* __restrict__ acsr,
                                                const float* __restrict__ Inv,
                                                float* __restrict__ wout) {
    int e = blockIdx.x * 256 + threadIdx.x;
    if (e >= EE) return;
    int d = ei[EE + e];
    float al = acsr[offs[d] + slot[e]];
    wout[e] = exp2f(al - QBIAS) * Inv[d];
}

// ---------------------------------------------------------------- heads
__global__ __launch_bounds__(256) void k_head(const float* __restrict__ h3,
                                              const float* __restrict__ fc1W,
                                              const float* __restrict__ fc1b,
                                              const float* __restrict__ Wc,
                                              const float* __restrict__ bc,
                                              const float* __restrict__ Wt,
                                              const float* __restrict__ bt,
                                              float* __restrict__ outp) {
    __shared__ float sW1[32 * 32];
    __shared__ float sWc[32 * NCLONE];
    __shared__ float sWt[32 * NTYPE];
    __shared__ float sb1[32], sbc[NCLONE], sbt[NTYPE];
    int tid = threadIdx.x;
    for (int i = tid; i < 1024; i += 256) sW1[i] = fc1W[i];
    for (int i = tid; i < 32 * NCLONE; i += 256) sWc[i] = Wc[i];
    for (int i = tid; i < 32 * NTYPE; i += 256) sWt[i] = Wt[i];
    if (tid < 32) sb1[tid] = fc1b[tid];
    if (tid < NCLONE) sbc[tid] = bc[tid];
    if (tid < NTYPE) sbt[tid] = bt[tid];
    __syncthreads();
    int g = tid >> 5, l = tid & 31;
    int v = blockIdx.x * 8 + g;
    if (v >= NN) return;
    float x = h3[(size_t)v * CCH + l];
    float acc = sb1[l];
    #pragma unroll
    for (int c = 0; c < 32; ++c) {
        float xc = __shfl(x, c, 32);
        acc += xc * sW1[c * 32 + l];
    }
    float hl = fmaxf(acc, 0.0f);
    float at = (l < NTYPE) ? sbt[l] : 0.0f;
    float ac = (l < NCLONE) ? sbc[l] : 0.0f;
    #pragma unroll
    for (int c = 0; c < 32; ++c) {
        float hc = __shfl(hl, c, 32);
        float wt_ = (l < NTYPE) ? sWt[c * NTYPE + l] : 0.0f;
        float wc_ = (l < NCLONE) ? sWc[c * NCLONE + l] : 0.0f;
        at += hc * wt_;
        ac += hc * wc_;
    }
    float vt = (l < NTYPE) ? at : -INFINITY;
    float mt = vt;
    mt = fmaxf(mt, __shfl_xor(mt, 16, 32));
    mt = fmaxf(mt, __shfl_xor(mt, 8, 32));
    mt = fmaxf(mt, __shfl_xor(mt, 4, 32));
    mt = fmaxf(mt, __shfl_xor(mt, 2, 32));
    mt = fmaxf(mt, __shfl_xor(mt, 1, 32));
    float et = __expf(vt - mt);
    float stt = et;
    stt += __shfl_xor(stt, 16, 32);
    stt += __shfl_xor(stt, 8, 32);
    stt += __shfl_xor(stt, 4, 32);
    stt += __shfl_xor(stt, 2, 32);
    stt += __shfl_xor(stt, 1, 32);
    float lt = vt - mt - logf(stt);
    float vc = (l < NCLONE) ? ac : -INFINITY;
    float mc = vc;
    mc = fmaxf(mc, __shfl_xor(mc, 16, 32));
    mc = fmaxf(mc, __shfl_xor(mc, 8, 32));
    mc = fmaxf(mc, __shfl_xor(mc, 4, 32));
    mc = fmaxf(mc, __shfl_xor(mc, 2, 32));
    mc = fmaxf(mc, __shfl_xor(mc, 1, 32));
    float ec = __expf(vc - mc);
    float sc = ec;
    sc += __shfl_xor(sc, 16, 32);
    sc += __shfl_xor(sc, 8, 32);
    sc += __shfl_xor(sc, 4, 32);
    sc += __shfl_xor(sc, 2, 32);
    sc += __shfl_xor(sc, 1, 32);
    float lc = vc - mc - logf(sc);
    size_t ob = (size_t)v * 48;
    if (l < NCLONE) outp[ob + l] = lc;
    if (l < NTYPE) outp[ob + NCLONE + l] = lt;
}

// ---------------------------------------------------------------- launcher
extern "C" void kernel_launch(void* const* d_in, const int* in_sizes, int n_in,
                              void* d_out, int out_size, void* d_ws, size_t ws_size,
                              hipStream_t stream) {
    const float* x     = (const float*)d_in[0];
    const int*   ei    = (const int*)d_in[1];
    const float* ea    = (const float*)d_in[2];
    const float* Wl1   = (const float*)d_in[3];
    const float* Wr1   = (const float*)d_in[4];
    const float* We1   = (const float*)d_in[5];
    const float* att1  = (const float*)d_in[6];
    const float* b1    = (const float*)d_in[7];
    const float* skipW = (const float*)d_in[8];
    const float* skipb = (const float*)d_in[9];
    const float* bng   = (const float*)d_in[10];
    const float* bnb   = (const float*)d_in[11];
    const float* Wl2   = (const float*)d_in[12];
    const float* Wr2   = (const float*)d_in[13];
    const float* We2   = (const float*)d_in[14];
    const float* att2  = (const float*)d_in[15];
    const float* b2    = (const float*)d_in[16];
    const float* fc1W  = (const float*)d_in[17];
    const float* fc1b  = (const float*)d_in[18];
    const float* Wc    = (const float*)d_in[19];
    const float* bc    = (const float*)d_in[20];
    const float* Wt    = (const float*)d_in[21];
    const float* bt    = (const float*)d_in[22];
    float* out = (float*)d_out;
    float* wout = out + (size_t)NN * 48;

    const size_t NF = (size_t)NN * FIN;   // 12.8M elems
    char* w = (char*)d_ws;
    fp16_t* xl1h = (fp16_t*)w;  w += NF * 2;
    fp16_t* xr1h = (fp16_t*)w;  w += NF * 2;
    fp16_t* skb  = (fp16_t*)w;  w += NF * 2;
    bf16_t* hb   = (bf16_t*)w;  w += NF * 2;
    int2*   ep8  = (int2*)w;    w += (size_t)EE * 8;
    float*  acsr = (float*)w;   w += (size_t)EE * 4;
    int*    slot = (int*)w;     w += (size_t)EE * 4;
    int* deg   = (int*)w;   w += (size_t)NN * 4;
    int* offs  = (int*)w;   w += (size_t)NN * 4;
    float* mattr = (float*)w; w += (size_t)NN * 4;
    float* Inv   = (float*)w; w += (size_t)NN * 4;
    int*   perm  = (int*)w;   w += (size_t)NN * 4;
    int*   bsum  = (int*)w;   w += 64 * 4;
    float* bns   = (float*)w; w += 128 * 4;
    float* bnq   = (float*)w; w += 128 * 4;
    int*   hist  = (int*)w;   w += NBIN * 4;
    int*   binpos= (int*)w;   w += NBIN * 4;
    float* scl   = (float*)w; w += 128 * 4;
    float* shf   = (float*)w; w += 128 * 4;
    bf16_t* WbT  = (bf16_t*)w; w += 384 * 128 * 2;
    bf16_t* Wb2T = (bf16_t*)w; w += 64 * 128 * 2;
    // aliases into dead regions (after gat1):
    fp16_t* xl2h = xl1h;              // 6.4 MB
    float*  xr2  = (float*)xr1h;      // 12.8 MB
    float*  h3   = (float*)skb;       // 12.8 MB

    hipMemsetAsync(deg, 0, (size_t)NN * sizeof(int), stream);
    hipMemsetAsync(bns, 0, (256 + NBIN) * sizeof(float), stream);   // bns + bnq + hist

    k_wcvt<<<224, 256, 0, stream>>>(Wl1, Wr1, skipW, Wl2, Wr2, WbT, Wb2T);

    k_deg<<<6250, 256, 0, stream>>>(ei, deg, slot);
    k_scan1<<<SCAN_B, 256, 0, stream>>>(deg, offs, bsum, hist);
    k_serial<<<1, 64, 0, stream>>>(bsum, hist, binpos);
    k_scat<<<391, 256, 0, stream>>>(deg, binpos, perm, offs, bsum);
    k_fill<<<6250, 256, 0, stream>>>(ei, ea, offs, slot, ep8);

    k_gemm1<<<782, 256, 0, stream>>>(x, WbT, xl1h, xr1h, skb);
    k_gat1<<<25000, 256, 0, stream>>>(perm, xl1h, xr1h, skb, offs, deg, ep8,
                                      att1, We1, b1, skipb, hb, mattr);
    k_bnstats<<<128, 256, 0, stream>>>(hb, bns, bnq);
    k_bnfinal<<<1, 128, 0, stream>>>(bns, bnq, bng, bnb, scl, shf);
    k_gemm2<<<782, 256, 0, stream>>>(hb, scl, shf, Wb2T, xl2h, xr2);
    k_gat2<<<25000, 256, 0, stream>>>(perm, xl2h, xr2, mattr, offs, deg, ep8,
                                      att2, We2, b2, h3, acsr, Inv, wout);
    k_wfinal<<<6250, 256, 0, stream>>>(ei, offs, slot, acsr, Inv, wout);
    k_head<<<12500, 256, 0, stream>>>(h3, fc1W, fc1b, Wc, bc, Wt, bt, out);
}

// Round 14
// 418.847 us; speedup vs baseline: 1.1801x; 1.0035x over previous
//
#include <hip/hip_runtime.h>
#include <math.h>

// Problem constants
#define NN 100000
#define EE 1600000
#define FIN 128
#define HCH 128     // H*C for gat1
#define CCH 32      // C
#define NCLONE 19
#define NTYPE 29
#define ETOT (EE + NN)
#define SCAN_B 49   // ceil(NN / 2048)
#define NBIN 128
#define LOG2E 1.4426950408889634f
#define QBIAS 5.0f

typedef __bf16 bf16_t;
typedef bf16_t bf16x8 __attribute__((ext_vector_type(8)));
typedef _Float16 fp16_t;
typedef fp16_t fp16x2 __attribute__((ext_vector_type(2)));
typedef fp16_t fp16x4 __attribute__((ext_vector_type(4)));
typedef fp16_t fp16x8 __attribute__((ext_vector_type(8)));
typedef float f32x4 __attribute__((ext_vector_type(4)));

static __device__ __forceinline__ fp16x2 shfl_p2(fp16x2 v, int mask) {
    float f = __shfl_xor(__builtin_bit_cast(float, v), mask, 64);
    return __builtin_bit_cast(fp16x2, f);
}
static __device__ __forceinline__ fp16x2 bc2(float f) {
    fp16_t h = (fp16_t)f;
    fp16x2 r = {h, h};
    return r;
}
// leaky_relu(w, 0.2) == max(w, 0.2*w)  -> v_pk_mul_f16 + v_pk_max_f16
static __device__ __forceinline__ fp16x2 leaky2(fp16x2 w) {
    const fp16x2 c02 = {(fp16_t)0.2f, (fp16_t)0.2f};
    return __builtin_elementwise_max(w, w * c02);
}
// f32 += a.lo*b.lo + a.hi*b.hi  (v_dot2_f32_f16 when available)
static __device__ __forceinline__ float dot2(fp16x2 a, fp16x2 b, float c) {
#if __has_builtin(__builtin_amdgcn_fdot2)
    return __builtin_amdgcn_fdot2(a, b, c, false);
#else
    return c + (float)(a[0] * b[0]) + (float)(a[1] * b[1]);
#endif
}

// ---------------------------------------------------------------- weight conversion
__global__ __launch_bounds__(256) void k_wcvt(const float* __restrict__ Wl1,
                                              const float* __restrict__ Wr1,
                                              const float* __restrict__ Ws,
                                              const float* __restrict__ Wl2,
                                              const float* __restrict__ Wr2,
                                              bf16_t* __restrict__ WbT,
                                              bf16_t* __restrict__ Wb2T) {
    int t = blockIdx.x * 256 + threadIdx.x;
    if (t < 384 * 128) {
        int n = t >> 7, k = t & 127;
        const float* W = (n < 128) ? Wl1 : ((n < 256) ? Wr1 : Ws);
        WbT[t] = (bf16_t)W[k * 128 + (n & 127)];
    } else if (t < 384 * 128 + 64 * 128) {
        int u = t - 384 * 128;
        int n = u >> 7, k = u & 127;
        const float* W = (n < 32) ? Wl2 : Wr2;
        Wb2T[u] = (bf16_t)W[k * 32 + (n & 31)];
    }
}

// ---------------------------------------------------------------- degree + slot
__global__ __launch_bounds__(256) void k_deg(const int* __restrict__ ei,
                                             int* __restrict__ deg,
                                             int* __restrict__ slot) {
    int e = blockIdx.x * 256 + threadIdx.x;
    if (e < EE) {
        int d = ei[EE + e];
        slot[e] = atomicAdd(&deg[d], 1);
    }
}

// ---------------------------------------------------------------- exclusive scan of deg + degree histogram (fused)
__global__ __launch_bounds__(256) void k_scan1(const int* __restrict__ deg,
                                               int* __restrict__ offs,
                                               int* __restrict__ bsum,
                                               int* __restrict__ hist) {
    __shared__ int tsum[256];
    __shared__ int lh[NBIN];
    int b = blockIdx.x, tid = threadIdx.x;
    if (tid < NBIN) lh[tid] = 0;
    int base = b * 2048;
    int loc[8], dv[8];
    int s = 0;
    #pragma unroll
    for (int i = 0; i < 8; ++i) {
        int idx = base + tid * 8 + i;
        int d = (idx < NN) ? deg[idx] : 0;
        dv[i] = (idx < NN) ? d : -1;
        loc[i] = s; s += d;
    }
    tsum[tid] = s;
    __syncthreads();
    #pragma unroll
    for (int i = 0; i < 8; ++i)
        if (dv[i] >= 0) atomicAdd(&lh[min(dv[i], NBIN - 1)], 1);
    for (int off = 1; off < 256; off <<= 1) {
        int v = (tid >= off) ? tsum[tid - off] : 0;
        __syncthreads();
        tsum[tid] += v;
        __syncthreads();
    }
    int texcl = tsum[tid] - s;
    #pragma unroll
    for (int i = 0; i < 8; ++i) {
        int idx = base + tid * 8 + i;
        if (idx < NN) offs[idx] = texcl + loc[i];
    }
    if (tid == 255) bsum[b] = tsum[255];
    __syncthreads();
    if (tid < NBIN && lh[tid]) atomicAdd(&hist[tid], lh[tid]);
}

// serial: bsum prefix + descending-degree binpos
__global__ void k_serial(int* __restrict__ bsum,
                         const int* __restrict__ hist,
                         int* __restrict__ binpos) {
    if (threadIdx.x == 0) {
        int run = 0;
        for (int i = 0; i < SCAN_B; ++i) { int t = bsum[i]; bsum[i] = run; run += t; }
        run = 0;
        for (int b = NBIN - 1; b >= 0; --b) { binpos[b] = run; run += hist[b]; }
    }
}

// scatter perm + offs fixup (fused former k_scan3)
__global__ __launch_bounds__(256) void k_scat(const int* __restrict__ deg,
                                              int* __restrict__ binpos,
                                              int* __restrict__ perm,
                                              int* __restrict__ offs,
                                              const int* __restrict__ bsum) {
    __shared__ int lcnt[NBIN];
    __shared__ int lbase[NBIN];
    int tid = threadIdx.x;
    if (tid < NBIN) lcnt[tid] = 0;
    __syncthreads();
    int v = blockIdx.x * 256 + tid;
    int b = 0, r = 0;
    bool ok = (v < NN);
    if (ok) {
        offs[v] += bsum[v >> 11];
        b = min(deg[v], NBIN - 1);
        r = atomicAdd(&lcnt[b], 1);
    }
    __syncthreads();
    if (tid < NBIN && lcnt[tid]) lbase[tid] = atomicAdd(&binpos[tid], lcnt[tid]);
    __syncthreads();
    if (ok) perm[lbase[b] + r] = v;
}

// ---------------------------------------------------------------- CSR fill (atomic-free)
__global__ __launch_bounds__(256) void k_fill(const int* __restrict__ ei,
                                              const float* __restrict__ ea,
                                              const int* __restrict__ offs,
                                              const int* __restrict__ slot,
                                              int2* __restrict__ ep8) {
    int e = blockIdx.x * 256 + threadIdx.x;
    if (e < EE) {
        int d = ei[EE + e];
        int pos = offs[d] + slot[e];
        ep8[pos] = make_int2(ei[e], __float_as_int(ea[e]));
    }
}

// ---------------------------------------------------------------- GEMM1 (MFMA): x(f32) @ WbT^T -> [xl1|xr1|skb] (fp16)
__global__ __launch_bounds__(256) void k_gemm1(const float* __restrict__ x,
                                               const bf16_t* __restrict__ WbT,
                                               fp16_t* __restrict__ xl,
                                               fp16_t* __restrict__ xr,
                                               fp16_t* __restrict__ sk) {
    __shared__ bf16_t As[128 * 128];
    __shared__ bf16_t Bs[128 * 128];
    const int tid = threadIdx.x;
    const int row0 = blockIdx.x * 128;
    #pragma unroll
    for (int i = 0; i < 8; ++i) {
        int c = i * 256 + tid;
        int r = c >> 4, g = c & 15;
        int gr = row0 + r;
        bf16x8 v = {};
        if (gr < NN) {
            float4 f0 = *(const float4*)(x + (size_t)gr * 128 + g * 8);
            float4 f1 = *(const float4*)(x + (size_t)gr * 128 + g * 8 + 4);
            v[0] = (bf16_t)f0.x; v[1] = (bf16_t)f0.y; v[2] = (bf16_t)f0.z; v[3] = (bf16_t)f0.w;
            v[4] = (bf16_t)f1.x; v[5] = (bf16_t)f1.y; v[6] = (bf16_t)f1.z; v[7] = (bf16_t)f1.w;
        }
        *(bf16x8*)&As[r * 128 + ((g ^ (r & 7)) * 8)] = v;
    }

    const int wid = tid >> 6, lane = tid & 63;
    const int wm = wid >> 1, wn = wid & 1;
    const int lr = lane & 15, lg = lane >> 4;

    for (int chunk = 0; chunk < 3; ++chunk) {
        const int col0 = chunk * 128;
        fp16_t* __restrict__ out = (chunk == 0) ? xl : ((chunk == 1) ? xr : sk);
        __syncthreads();
        #pragma unroll
        for (int i = 0; i < 8; ++i) {
            int c = i * 256 + tid;
            int n = c >> 4, g = c & 15;
            bf16x8 v = *(const bf16x8*)(WbT + (size_t)(col0 + n) * 128 + g * 8);
            *(bf16x8*)&Bs[n * 128 + ((g ^ (n & 7)) * 8)] = v;
        }
        __syncthreads();

        f32x4 acc[4][4] = {};
        #pragma unroll
        for (int ks = 0; ks < 4; ++ks) {
            int g = ks * 4 + lg;
            bf16x8 b[4];
            #pragma unroll
            for (int ni = 0; ni < 4; ++ni) {
                int n = wn * 64 + ni * 16 + lr;
                b[ni] = *(const bf16x8*)&Bs[n * 128 + ((g ^ (n & 7)) * 8)];
            }
            #pragma unroll
            for (int mi = 0; mi < 4; ++mi) {
                int r = wm * 64 + mi * 16 + lr;
                bf16x8 a = *(const bf16x8*)&As[r * 128 + ((g ^ (r & 7)) * 8)];
                #pragma unroll
                for (int ni = 0; ni < 4; ++ni)
                    acc[mi][ni] = __builtin_amdgcn_mfma_f32_16x16x32_bf16(a, b[ni], acc[mi][ni], 0, 0, 0);
            }
        }
        #pragma unroll
        for (int mi = 0; mi < 4; ++mi)
            #pragma unroll
            for (int ni = 0; ni < 4; ++ni)
                #pragma unroll
                for (int j = 0; j < 4; ++j) {
                    int gr = row0 + wm * 64 + mi * 16 + lg * 4 + j;
                    if (gr >= NN) continue;
                    int n = wn * 64 + ni * 16 + lr;
                    out[(size_t)gr * 128 + n] = (fp16_t)acc[mi][ni][j];
                }
    }
}

// ---------------------------------------------------------------- GAT1: packed-fp16, 16 lanes x 8ch per edge, 4 subgroups, depth-3
// score via v_dot2_f32_f16; QBIAS folded into accumulator init (-QBIAS/4 per lane).
__global__ __launch_bounds__(256) void k_gat1(const int* __restrict__ perm,
                                              const fp16_t* __restrict__ xl1,
                                              const fp16_t* __restrict__ xr1,
                                              const fp16_t* __restrict__ skb,
                                              const int* __restrict__ offs,
                                              const int* __restrict__ deg,
                                              const int2* __restrict__ ep8,
                                              const float* __restrict__ att1,
                                              const float* __restrict__ we1,
                                              const float* __restrict__ b1,
                                              const float* __restrict__ skipb,
                                              bf16_t* __restrict__ hb,
                                              float* __restrict__ mattr) {
    int gid = (blockIdx.x * 256 + threadIdx.x) >> 6;
    if (gid >= NN) return;
    int v = perm[gid];
    int lane = threadIdx.x & 63;
    int sub = lane >> 4;
    int l = lane & 15;
    int c0 = l * 8;
    fp16x2 at2[4], we2[4], xr2v[4];
    {
        float4 t0 = *(const float4*)(att1 + c0);
        float4 t1 = *(const float4*)(att1 + c0 + 4);
        at2[0] = fp16x2{(fp16_t)(t0.x * LOG2E), (fp16_t)(t0.y * LOG2E)};
        at2[1] = fp16x2{(fp16_t)(t0.z * LOG2E), (fp16_t)(t0.w * LOG2E)};
        at2[2] = fp16x2{(fp16_t)(t1.x * LOG2E), (fp16_t)(t1.y * LOG2E)};
        at2[3] = fp16x2{(fp16_t)(t1.z * LOG2E), (fp16_t)(t1.w * LOG2E)};
        float4 w0 = *(const float4*)(we1 + c0);
        float4 w1 = *(const float4*)(we1 + c0 + 4);
        we2[0] = fp16x2{(fp16_t)w0.x, (fp16_t)w0.y};
        we2[1] = fp16x2{(fp16_t)w0.z, (fp16_t)w0.w};
        we2[2] = fp16x2{(fp16_t)w1.x, (fp16_t)w1.y};
        we2[3] = fp16x2{(fp16_t)w1.z, (fp16_t)w1.w};
        fp16x8 xrv = *(const fp16x8*)(xr1 + (size_t)v * 128 + c0);
        const fp16x2* xp = (const fp16x2*)&xrv;
        xr2v[0] = xp[0]; xr2v[1] = xp[1]; xr2v[2] = xp[2]; xr2v[3] = xp[3];
    }
    float den = 0.f, easum = 0.f;
    fp16x2 n2[4] = {};
    int st = offs[v], dg = deg[v];
    int i = sub;
    int2 e0 = make_int2(0, 0), e1 = make_int2(0, 0), e2 = make_int2(0, 0);
    fp16x8 a0 = {}, a1 = {};
    if (i < dg) e0 = ep8[st + i];
    if (i + 4 < dg) e1 = ep8[st + i + 4];
    if (i + 8 < dg) e2 = ep8[st + i + 8];
    if (i < dg) a0 = *(const fp16x8*)(xl1 + (size_t)e0.x * 128 + c0);
    if (i + 4 < dg) a1 = *(const fp16x8*)(xl1 + (size_t)e1.x * 128 + c0);

#define GAT1_BODY                                                    \
    {                                                                \
        float ea_ = __int_as_float(e0.y);                            \
        easum += ea_;                                                \
        fp16x2 ea2 = bc2(ea_);                                       \
        const fp16x2* xp = (const fp16x2*)&a0;                       \
        float q = -(QBIAS / 4.0f);                                   \
        _Pragma("unroll")                                            \
        for (int j = 0; j < 4; ++j) {                                \
            fp16x2 w = xp[j] + (ea2 * we2[j] + xr2v[j]);             \
            w = leaky2(w);                                           \
            q = dot2(w, at2[j], q);                                  \
        }                                                            \
        q += __shfl_xor(q, 1, 4);                                    \
        q += __shfl_xor(q, 2, 4);                                    \
        float ex = exp2f(q);                                         \
        den += ex;                                                   \
        fp16x2 ex2 = bc2(ex);                                        \
        _Pragma("unroll")                                            \
        for (int j = 0; j < 4; ++j) n2[j] = n2[j] + ex2 * xp[j];     \
        e0 = e1; e1 = e2; e2 = e3; a0 = a1; a1 = a2;                 \
    }

    #pragma unroll 2
    for (; i + 12 < dg; i += 4) {
        fp16x8 a2 = *(const fp16x8*)(xl1 + (size_t)e2.x * 128 + c0);
        int2 e3 = ep8[st + i + 12];
        GAT1_BODY
    }
    for (; i < dg; i += 4) {
        fp16x8 a2 = {};
        int2 e3 = make_int2(0, 0);
        if (i + 8 < dg) a2 = *(const fp16x8*)(xl1 + (size_t)e2.x * 128 + c0);
        GAT1_BODY
    }
#undef GAT1_BODY

    // merge 4 subgroup states (plain sums)
    #pragma unroll
    for (int w_ = 16; w_ <= 32; w_ <<= 1) {
        den += __shfl_xor(den, w_, 64);
        easum += __shfl_xor(easum, w_, 64);
        #pragma unroll
        for (int j = 0; j < 4; ++j) n2[j] = n2[j] + shfl_p2(n2[j], w_);
    }
    // unpack n to f32
    float n[8];
    #pragma unroll
    for (int j = 0; j < 4; ++j) { n[2 * j] = (float)n2[j][0]; n[2 * j + 1] = (float)n2[j][1]; }
    // self loop (mean edge attr)
    float eav = easum / fmaxf((float)dg, 1.0f);
    if (lane == 0) mattr[v] = eav;
    fp16x8 svv = *(const fp16x8*)(xl1 + (size_t)v * 128 + c0);
    const fp16x2* xsp = (const fp16x2*)&svv;
    {
        fp16x2 ea2 = bc2(eav);
        float qs = -(QBIAS / 4.0f);
        #pragma unroll
        for (int j = 0; j < 4; ++j) {
            fp16x2 w = xsp[j] + (ea2 * we2[j] + xr2v[j]);
            w = leaky2(w);
            qs = dot2(w, at2[j], qs);
        }
        qs += __shfl_xor(qs, 1, 4);
        qs += __shfl_xor(qs, 2, 4);
        float ex = exp2f(qs);
        den += ex;
        #pragma unroll
        for (int j = 0; j < 4; ++j) {
            n[2 * j]     = fmaf(ex, (float)xsp[j][0], n[2 * j]);
            n[2 * j + 1] = fmaf(ex, (float)xsp[j][1], n[2 * j + 1]);
        }
    }
    if (sub == 0) {
        float inv = 1.0f / (den + 1e-16f);
        float4 bb0 = *(const float4*)(b1 + c0);
        float4 bb1 = *(const float4*)(b1 + c0 + 4);
        float4 sb0 = *(const float4*)(skipb + c0);
        float4 sb1 = *(const float4*)(skipb + c0 + 4);
        fp16x8 skv = *(const fp16x8*)(skb + (size_t)v * 128 + c0);
        float bb[8] = {bb0.x, bb0.y, bb0.z, bb0.w, bb1.x, bb1.y, bb1.z, bb1.w};
        float sv[8] = {sb0.x, sb0.y, sb0.z, sb0.w, sb1.x, sb1.y, sb1.z, sb1.w};
        bf16x8 r;
        #pragma unroll
        for (int j = 0; j < 8; ++j)
            r[j] = (bf16_t)(n[j] * inv + bb[j] + (float)skv[j] + sv[j]);
        *(bf16x8*)(hb + (size_t)v * 128 + c0) = r;
    }
}

// ---------------------------------------------------------------- batchnorm stats
__global__ __launch_bounds__(256) void k_bnstats(const bf16_t* __restrict__ h,
                                                 float* __restrict__ bns,
                                                 float* __restrict__ bnq) {
    __shared__ float sS[16 * 128];
    __shared__ float sQ[16 * 128];
    int tid = threadIdx.x;
    int cg = tid & 15;
    int slot = tid >> 4;
    int c0 = cg * 8;
    float s[8] = {}, q[8] = {};
    for (int r = blockIdx.x * 16 + slot; r < NN; r += gridDim.x * 16) {
        bf16x8 v = *(const bf16x8*)&h[(size_t)r * 128 + c0];
        #pragma unroll
        for (int j = 0; j < 8; ++j) { float f = (float)v[j]; s[j] += f; q[j] += f * f; }
    }
    #pragma unroll
    for (int j = 0; j < 8; ++j) { sS[slot * 128 + c0 + j] = s[j]; sQ[slot * 128 + c0 + j] = q[j]; }
    __syncthreads();
    if (tid < 128) {
        float as = 0.f, aq = 0.f;
        #pragma unroll
        for (int k = 0; k < 16; ++k) { as += sS[k * 128 + tid]; aq += sQ[k * 128 + tid]; }
        atomicAdd(&bns[tid], as);
        atomicAdd(&bnq[tid], aq);
    }
}

__global__ void k_bnfinal(const float* __restrict__ bns, const float* __restrict__ bnq,
                          const float* __restrict__ g, const float* __restrict__ b,
                          float* __restrict__ scale, float* __restrict__ shift) {
    int c = threadIdx.x;
    if (c < 128) {
        float mu = bns[c] * (1.0f / NN);
        float var = bnq[c] * (1.0f / NN) - mu * mu;
        float rs = rsqrtf(var + 1e-5f);
        float a = rs * g[c];
        scale[c] = a;
        shift[c] = b[c] - mu * a;
    }
}

// ---------------------------------------------------------------- GEMM2 (MFMA): elu(bn(h_bf16)) @ Wb2T^T -> [xl2 fp16 | xr2 f32]
__global__ __launch_bounds__(256) void k_gemm2(const bf16_t* __restrict__ h,
                                               const float* __restrict__ scl,
                                               const float* __restrict__ shf,
                                               const bf16_t* __restrict__ Wb2T,
                                               fp16_t* __restrict__ xl2,
                                               float* __restrict__ xr2) {
    __shared__ bf16_t As[128 * 128];
    __shared__ bf16_t Bs[64 * 128];
    const int tid = threadIdx.x;
    const int row0 = blockIdx.x * 128;
    #pragma unroll
    for (int i = 0; i < 8; ++i) {
        int c = i * 256 + tid;
        int r = c >> 4, g = c & 15;
        int gr = row0 + r;
        bf16x8 v = {};
        if (gr < NN) {
            bf16x8 hv = *(const bf16x8*)(h + (size_t)gr * 128 + g * 8);
            float4 s0 = *(const float4*)(scl + g * 8);
            float4 s1 = *(const float4*)(scl + g * 8 + 4);
            float4 t0 = *(const float4*)(shf + g * 8);
            float4 t1 = *(const float4*)(shf + g * 8 + 4);
            float e[8];
            e[0] = (float)hv[0] * s0.x + t0.x; e[1] = (float)hv[1] * s0.y + t0.y;
            e[2] = (float)hv[2] * s0.z + t0.z; e[3] = (float)hv[3] * s0.w + t0.w;
            e[4] = (float)hv[4] * s1.x + t1.x; e[5] = (float)hv[5] * s1.y + t1.y;
            e[6] = (float)hv[6] * s1.z + t1.z; e[7] = (float)hv[7] * s1.w + t1.w;
            #pragma unroll
            for (int j = 0; j < 8; ++j) {
                float vv = e[j];
                vv = (vv > 0.f) ? vv : (__expf(vv) - 1.0f);
                v[j] = (bf16_t)vv;
            }
        }
        *(bf16x8*)&As[r * 128 + ((g ^ (r & 7)) * 8)] = v;
    }
    #pragma unroll
    for (int i = 0; i < 4; ++i) {
        int c = i * 256 + tid;
        int n = c >> 4, g = c & 15;
        bf16x8 v = *(const bf16x8*)(Wb2T + (size_t)n * 128 + g * 8);
        *(bf16x8*)&Bs[n * 128 + ((g ^ (n & 7)) * 8)] = v;
    }
    __syncthreads();

    const int wid = tid >> 6, lane = tid & 63;
    const int wm = wid >> 1, wn = wid & 1;
    const int lr = lane & 15, lg = lane >> 4;
    f32x4 acc[4][2] = {};
    #pragma unroll
    for (int ks = 0; ks < 4; ++ks) {
        int g = ks * 4 + lg;
        bf16x8 b0, b1;
        {
            int n = wn * 32 + lr;
            b0 = *(const bf16x8*)&Bs[n * 128 + ((g ^ (n & 7)) * 8)];
            n += 16;
            b1 = *(const bf16x8*)&Bs[n * 128 + ((g ^ (n & 7)) * 8)];
        }
        #pragma unroll
        for (int mi = 0; mi < 4; ++mi) {
            int r = wm * 64 + mi * 16 + lr;
            bf16x8 a = *(const bf16x8*)&As[r * 128 + ((g ^ (r & 7)) * 8)];
            acc[mi][0] = __builtin_amdgcn_mfma_f32_16x16x32_bf16(a, b0, acc[mi][0], 0, 0, 0);
            acc[mi][1] = __builtin_amdgcn_mfma_f32_16x16x32_bf16(a, b1, acc[mi][1], 0, 0, 0);
        }
    }
    #pragma unroll
    for (int mi = 0; mi < 4; ++mi)
        #pragma unroll
        for (int ni = 0; ni < 2; ++ni)
            #pragma unroll
            for (int j = 0; j < 4; ++j) {
                int gr = row0 + wm * 64 + mi * 16 + lg * 4 + j;
                if (gr >= NN) continue;
                int n = wn * 32 + ni * 16 + lr;
                float val = acc[mi][ni][j];
                if (n < 32) xl2[(size_t)gr * 32 + n] = (fp16_t)val;
                else xr2[(size_t)gr * 32 + (n - 32)] = val;
            }
}

// ---------------------------------------------------------------- GAT2: packed-fp16, 8 lanes x 4ch per edge, 8 subgroups, depth-3
// score via v_dot2_f32_f16; QBIAS folded into accumulator init (-QBIAS/8 per lane).
__global__ __launch_bounds__(256) void k_gat2(const int* __restrict__ perm,
                                              const fp16_t* __restrict__ xl2,
                                              const float* __restrict__ xr2,
                                              const float* __restrict__ mattr,
                                              const int* __restrict__ offs,
                                              const int* __restrict__ deg,
                                              const int2* __restrict__ ep8,
                                              const float* __restrict__ att2,
                                              const float* __restrict__ we2_,
                                              const float* __restrict__ b2,
                                              float* __restrict__ h3,
                                              float* __restrict__ acsr,
                                              float* __restrict__ Inv,
                                              float* __restrict__ wout) {
    int gid = (blockIdx.x * 256 + threadIdx.x) >> 6;
    if (gid >= NN) return;
    int v = perm[gid];
    int lane = threadIdx.x & 63;
    int sub = lane >> 3;
    int l = lane & 7;
    int c0 = l * 4;
    fp16x2 at2[2], we2[2], xr2v[2];
    {
        float4 atv = *(const float4*)(att2 + c0);
        float4 wev = *(const float4*)(we2_ + c0);
        float4 xrv = *(const float4*)(xr2 + (size_t)v * 32 + c0);
        at2[0] = fp16x2{(fp16_t)(atv.x * LOG2E), (fp16_t)(atv.y * LOG2E)};
        at2[1] = fp16x2{(fp16_t)(atv.z * LOG2E), (fp16_t)(atv.w * LOG2E)};
        we2[0] = fp16x2{(fp16_t)wev.x, (fp16_t)wev.y};
        we2[1] = fp16x2{(fp16_t)wev.z, (fp16_t)wev.w};
        xr2v[0] = fp16x2{(fp16_t)xrv.x, (fp16_t)xrv.y};
        xr2v[1] = fp16x2{(fp16_t)xrv.z, (fp16_t)xrv.w};
    }
    float den = 0.f;
    fp16x2 n2[2] = {};
    int st = offs[v], dg = deg[v];
    int i = sub;
    int2 e0 = make_int2(0, 0), e1 = make_int2(0, 0), e2 = make_int2(0, 0);
    fp16x4 a0 = {}, a1 = {};
    if (i < dg) e0 = ep8[st + i];
    if (i + 8 < dg) e1 = ep8[st + i + 8];
    if (i + 16 < dg) e2 = ep8[st + i + 16];
    if (i < dg) a0 = *(const fp16x4*)(xl2 + (size_t)e0.x * 32 + c0);
    if (i + 8 < dg) a1 = *(const fp16x4*)(xl2 + (size_t)e1.x * 32 + c0);

#define GAT2_BODY                                                    \
    {                                                                \
        float ea_ = __int_as_float(e0.y);                            \
        fp16x2 ea2 = bc2(ea_);                                       \
        const fp16x2* xp = (const fp16x2*)&a0;                       \
        float q = -(QBIAS / 8.0f);                                   \
        _Pragma("unroll")                                            \
        for (int j = 0; j < 2; ++j) {                                \
            fp16x2 w = xp[j] + (ea2 * we2[j] + xr2v[j]);             \
            w = leaky2(w);                                           \
            q = dot2(w, at2[j], q);                                  \
        }                                                            \
        q += __shfl_xor(q, 1, 8);                                    \
        q += __shfl_xor(q, 2, 8);                                    \
        q += __shfl_xor(q, 4, 8);                                    \
        if (l == 0) acsr[st + i] = q;                                \
        float ex = exp2f(q);                                         \
        den += ex;                                                   \
        fp16x2 ex2 = bc2(ex);                                        \
        _Pragma("unroll")                                            \
        for (int j = 0; j < 2; ++j) n2[j] = n2[j] + ex2 * xp[j];     \
        e0 = e1; e1 = e2; e2 = e3; a0 = a1; a1 = a2;                 \
    }

    #pragma unroll 2
    for (; i + 24 < dg; i += 8) {
        fp16x4 a2 = *(const fp16x4*)(xl2 + (size_t)e2.x * 32 + c0);
        int2 e3 = ep8[st + i + 24];
        GAT2_BODY
    }
    for (; i < dg; i += 8) {
        fp16x4 a2 = {};
        int2 e3 = make_int2(0, 0);
        if (i + 16 < dg) a2 = *(const fp16x4*)(xl2 + (size_t)e2.x * 32 + c0);
        GAT2_BODY
    }
#undef GAT2_BODY

    // merge 8 subgroup states (plain sums)
    #pragma unroll
    for (int w_ = 8; w_ <= 32; w_ <<= 1) {
        den += __shfl_xor(den, w_, 64);
        #pragma unroll
        for (int j = 0; j < 2; ++j) n2[j] = n2[j] + shfl_p2(n2[j], w_);
    }
    float n[4] = {(float)n2[0][0], (float)n2[0][1], (float)n2[1][0], (float)n2[1][1]};
    // self loop
    float eav = mattr[v];
    fp16x4 sv = *(const fp16x4*)(xl2 + (size_t)v * 32 + c0);
    const fp16x2* xsp = (const fp16x2*)&sv;
    float qs;
    {
        fp16x2 ea2 = bc2(eav);
        qs = -(QBIAS / 8.0f);
        #pragma unroll
        for (int j = 0; j < 2; ++j) {
            fp16x2 w = xsp[j] + (ea2 * we2[j] + xr2v[j]);
            w = leaky2(w);
            qs = dot2(w, at2[j], qs);
        }
        qs += __shfl_xor(qs, 1, 8);
        qs += __shfl_xor(qs, 2, 8);
        qs += __shfl_xor(qs, 4, 8);
        float ex = exp2f(qs);
        den += ex;
        n[0] = fmaf(ex, (float)xsp[0][0], n[0]);
        n[1] = fmaf(ex, (float)xsp[0][1], n[1]);
        n[2] = fmaf(ex, (float)xsp[1][0], n[2]);
        n[3] = fmaf(ex, (float)xsp[1][1], n[3]);
    }
    float inv = 1.0f / (den + 1e-16f);
    if (lane == 0) {
        Inv[v] = inv;
        wout[EE + v] = exp2f(qs) * inv;
    }
    if (sub == 0) {
        float4 bb = *(const float4*)(b2 + c0);
        float b_[4] = {bb.x, bb.y, bb.z, bb.w};
        float4 r;
        float* rp = &r.x;
        #pragma unroll
        for (int j = 0; j < 4; ++j) {
            float o = n[j] * inv + b_[j];
            rp[j] = (o > 0.f) ? o : (__expf(o) - 1.0f);
        }
        *(float4*)(h3 + (size_t)v * 32 + c0) = r;
    }
}

// ---------------------------------------------------------------- finalize attention weights (original edge order)
__global__ __launch_bounds__(256) void k_wfinal(const int* __restrict__ ei,
                                                const int* __restrict__ offs,
                                                const int* __restrict__ slot,
                                                const float* __restrict__ acsr,
                                                const float* __restrict__ Inv,
                                                float* __restrict__ wout) {
    int e = blockIdx.x * 256 + threadIdx.x;
    if (e >= EE) return;
    int d = ei[EE + e];
    float al = acsr[offs[d] + slot[e]];   // already biased
    wout[e] = exp2f(al) * Inv[d];
}

// ---------------------------------------------------------------- heads
__global__ __launch_bounds__(256) void k_head(const float* __restrict__ h3,
                                              const float* __restrict__ fc1W,
                                              const float* __restrict__ fc1b,
                                              const float* __restrict__ Wc,
                                              const float* __restrict__ bc,
                                              const float* __restrict__ Wt,
                                              const float* __restrict__ bt,
                                              float* __restrict__ outp) {
    __shared__ float sW1[32 * 32];
    __shared__ float sWc[32 * NCLONE];
    __shared__ float sWt[32 * NTYPE];
    __shared__ float sb1[32], sbc[NCLONE], sbt[NTYPE];
    int tid = threadIdx.x;
    for (int i = tid; i < 1024; i += 256) sW1[i] = fc1W[i];
    for (int i = tid; i < 32 * NCLONE; i += 256) sWc[i] = Wc[i];
    for (int i = tid; i < 32 * NTYPE; i += 256) sWt[i] = Wt[i];
    if (tid < 32) sb1[tid] = fc1b[tid];
    if (tid < NCLONE) sbc[tid] = bc[tid];
    if (tid < NTYPE) sbt[tid] = bt[tid];
    __syncthreads();
    int g = tid >> 5, l = tid & 31;
    int v = blockIdx.x * 8 + g;
    if (v >= NN) return;
    float x = h3[(size_t)v * CCH + l];
    float acc = sb1[l];
    #pragma unroll
    for (int c = 0; c < 32; ++c) {
        float xc = __shfl(x, c, 32);
        acc += xc * sW1[c * 32 + l];
    }
    float hl = fmaxf(acc, 0.0f);
    float at = (l < NTYPE) ? sbt[l] : 0.0f;
    float ac = (l < NCLONE) ? sbc[l] : 0.0f;
    #pragma unroll
    for (int c = 0; c < 32; ++c) {
        float hc = __shfl(hl, c, 32);
        float wt_ = (l < NTYPE) ? sWt[c * NTYPE + l] : 0.0f;
        float wc_ = (l < NCLONE) ? sWc[c * NCLONE + l] : 0.0f;
        at += hc * wt_;
        ac += hc * wc_;
    }
    float vt = (l < NTYPE) ? at : -INFINITY;
    float mt = vt;
    mt = fmaxf(mt, __shfl_xor(mt, 16, 32));
    mt = fmaxf(mt, __shfl_xor(mt, 8, 32));
    mt = fmaxf(mt, __shfl_xor(mt, 4, 32));
    mt = fmaxf(mt, __shfl_xor(mt, 2, 32));
    mt = fmaxf(mt, __shfl_xor(mt, 1, 32));
    float et = __expf(vt - mt);
    float stt = et;
    stt += __shfl_xor(stt, 16, 32);
    stt += __shfl_xor(stt, 8, 32);
    stt += __shfl_xor(stt, 4, 32);
    stt += __shfl_xor(stt, 2, 32);
    stt += __shfl_xor(stt, 1, 32);
    float lt = vt - mt - logf(stt);
    float vc = (l < NCLONE) ? ac : -INFINITY;
    float mc = vc;
    mc = fmaxf(mc, __shfl_xor(mc, 16, 32));
    mc = fmaxf(mc, __shfl_xor(mc, 8, 32));
    mc = fmaxf(mc, __shfl_xor(mc, 4, 32));
    mc = fmaxf(mc, __shfl_xor(mc, 2, 32));
    mc = fmaxf(mc, __shfl_xor(mc, 1, 32));
    float ec = __expf(vc - mc);
    float sc = ec;
    sc += __shfl_xor(sc, 16, 32);
    sc += __shfl_xor(sc, 8, 32);
    sc += __shfl_xor(sc, 4, 32);
    sc += __shfl_xor(sc, 2, 32);
    sc += __shfl_xor(sc, 1, 32);
    float lc = vc - mc - logf(sc);
    size_t ob = (size_t)v * 48;
    if (l < NCLONE) outp[ob + l] = lc;
    if (l < NTYPE) outp[ob + NCLONE + l] = lt;
}

// ---------------------------------------------------------------- launcher
extern "C" void kernel_launch(void* const* d_in, const int* in_sizes, int n_in,
                              void* d_out, int out_size, void* d_ws, size_t ws_size,
                              hipStream_t stream) {
    const float* x     = (const float*)d_in[0];
    const int*   ei    = (const int*)d_in[1];
    const float* ea    = (const float*)d_in[2];
    const float* Wl1   = (const float*)d_in[3];
    const float* Wr1   = (const float*)d_in[4];
    const float* We1   = (const float*)d_in[5];
    const float* att1  = (const float*)d_in[6];
    const float* b1    = (const float*)d_in[7];
    const float* skipW = (const float*)d_in[8];
    const float* skipb = (const float*)d_in[9];
    const float* bng   = (const float*)d_in[10];
    const float* bnb   = (const float*)d_in[11];
    const float* Wl2   = (const float*)d_in[12];
    const float* Wr2   = (const float*)d_in[13];
    const float* We2   = (const float*)d_in[14];
    const float* att2  = (const float*)d_in[15];
    const float* b2    = (const float*)d_in[16];
    const float* fc1W  = (const float*)d_in[17];
    const float* fc1b  = (const float*)d_in[18];
    const float* Wc    = (const float*)d_in[19];
    const float* bc    = (const float*)d_in[20];
    const float* Wt    = (const float*)d_in[21];
    const float* bt    = (const float*)d_in[22];
    float* out = (float*)d_out;
    float* wout = out + (size_t)NN * 48;

    const size_t NF = (size_t)NN * FIN;   // 12.8M elems
    char* w = (char*)d_ws;
    fp16_t* xl1h = (fp16_t*)w;  w += NF * 2;
    fp16_t* xr1h = (fp16_t*)w;  w += NF * 2;
    fp16_t* skb  = (fp16_t*)w;  w += NF * 2;
    bf16_t* hb   = (bf16_t*)w;  w += NF * 2;
    int2*   ep8  = (int2*)w;    w += (size_t)EE * 8;
    float*  acsr = (float*)w;   w += (size_t)EE * 4;
    int*    slot = (int*)w;     w += (size_t)EE * 4;
    int* deg   = (int*)w;   w += (size_t)NN * 4;
    int* offs  = (int*)w;   w += (size_t)NN * 4;
    float* mattr = (float*)w; w += (size_t)NN * 4;
    float* Inv   = (float*)w; w += (size_t)NN * 4;
    int*   perm  = (int*)w;   w += (size_t)NN * 4;
    int*   bsum  = (int*)w;   w += 64 * 4;
    float* bns   = (float*)w; w += 128 * 4;
    float* bnq   = (float*)w; w += 128 * 4;
    int*   hist  = (int*)w;   w += NBIN * 4;
    int*   binpos= (int*)w;   w += NBIN * 4;
    float* scl   = (float*)w; w += 128 * 4;
    float* shf   = (float*)w; w += 128 * 4;
    bf16_t* WbT  = (bf16_t*)w; w += 384 * 128 * 2;
    bf16_t* Wb2T = (bf16_t*)w; w += 64 * 128 * 2;
    // aliases into dead regions (after gat1):
    fp16_t* xl2h = xl1h;              // 6.4 MB
    float*  xr2  = (float*)xr1h;      // 12.8 MB
    float*  h3   = (float*)skb;       // 12.8 MB

    hipMemsetAsync(deg, 0, (size_t)NN * sizeof(int), stream);
    hipMemsetAsync(bns, 0, (256 + NBIN) * sizeof(float), stream);   // bns + bnq + hist

    k_wcvt<<<224, 256, 0, stream>>>(Wl1, Wr1, skipW, Wl2, Wr2, WbT, Wb2T);

    k_deg<<<6250, 256, 0, stream>>>(ei, deg, slot);
    k_scan1<<<SCAN_B, 256, 0, stream>>>(deg, offs, bsum, hist);
    k_serial<<<1, 64, 0, stream>>>(bsum, hist, binpos);
    k_scat<<<391, 256, 0, stream>>>(deg, binpos, perm, offs, bsum);
    k_fill<<<6250, 256, 0, stream>>>(ei, ea, offs, slot, ep8);

    k_gemm1<<<782, 256, 0, stream>>>(x, WbT, xl1h, xr1h, skb);
    k_gat1<<<25000, 256, 0, stream>>>(perm, xl1h, xr1h, skb, offs, deg, ep8,
                                      att1, We1, b1, skipb, hb, mattr);
    k_bnstats<<<128, 256, 0, stream>>>(hb, bns, bnq);
    k_bnfinal<<<1, 128, 0, stream>>>(bns, bnq, bng, bnb, scl, shf);
    k_gemm2<<<782, 256, 0, stream>>>(hb, scl, shf, Wb2T, xl2h, xr2);
    k_gat2<<<25000, 256, 0, stream>>>(perm, xl2h, xr2, mattr, offs, deg, ep8,
                                      att2, We2, b2, h3, acsr, Inv, wout);
    k_wfinal<<<6250, 256, 0, stream>>>(ei, offs, slot, acsr, Inv, wout);
    k_head<<<12500, 256, 0, stream>>>(h3, fc1W, fc1b, Wc, bc, Wt, bt, out);
}